// Round 1
// baseline (410.985 us; speedup 1.0000x reference)
//
#include <hip/hip_runtime.h>
#include <hip/hip_bf16.h>

typedef __bf16 bf16;
typedef bf16 bf16x8 __attribute__((ext_vector_type(8)));
typedef float f32x4 __attribute__((ext_vector_type(4)));

#define EPI_BIAS_RELU 0
#define EPI_BIAS_BF16 1
#define EPI_SCALE_F32 2
#define EPI_RESID     3
#define EPI_BIAS_F32  4

__device__ __forceinline__ void lds_load16(const bf16* g, bf16* l) {
  __builtin_amdgcn_global_load_lds((__attribute__((address_space(1))) void*)g,
                                   (__attribute__((address_space(3))) void*)l,
                                   16, 0, 0);
}

// C = A (M x K, row-major, lda) * B^T (B is N x K row-major, ldb), epilogue fused.
// Tile 128x128, BK=32, 4 waves (2x2 of 64x64), 16x16x32 bf16 MFMA.
template<int EPI>
__global__ __launch_bounds__(256)
void gemm_bt(const bf16* __restrict__ A, const bf16* __restrict__ B,
             void* __restrict__ Cv, const float* __restrict__ bias,
             const bf16* __restrict__ resid,
             int K, int lda, int ldb, int ldc,
             long long sAz, long long sBz, long long sCz, long long sRz,
             float scale)
{
  __shared__ __align__(16) bf16 lA[128 * 32];
  __shared__ __align__(16) bf16 lB[128 * 32];
  const int z = blockIdx.z;
  const bf16* Ab = A + (size_t)z * sAz;
  const bf16* Bb = B + (size_t)z * sBz;
  const int row0 = blockIdx.y * 128, col0 = blockIdx.x * 128;
  const int tid = threadIdx.x, w = tid >> 6, l = tid & 63;
  const int wr = w >> 1, wc = w & 1;

  // staging: each wave fills 2x 1024B chunks of lA and lB (linear LDS, per-lane global addr)
  const int srow = 32 * w + (l >> 2);     // row within tile for this lane's 16B
  const int scol = (l & 3) * 8;           // element offset within row
  const bf16* gA0 = Ab + (size_t)(row0 + srow) * lda + scol;
  const bf16* gA1 = gA0 + (size_t)16 * lda;
  const bf16* gB0 = Bb + (size_t)(col0 + srow) * ldb + scol;
  const bf16* gB1 = gB0 + (size_t)16 * ldb;
  bf16* lAw0 = &lA[(2 * w) * 512];
  bf16* lAw1 = &lA[(2 * w + 1) * 512];
  bf16* lBw0 = &lB[(2 * w) * 512];
  bf16* lBw1 = &lB[(2 * w + 1) * 512];

  // fragment read bases: lane l reads row (l&15), k-offset (l>>4)*8
  const int fr = l & 15, fk = (l >> 4) * 8;
  const bf16* fA = &lA[(size_t)(wr * 64 + fr) * 32 + fk];
  const bf16* fB = &lB[(size_t)(wc * 64 + fr) * 32 + fk];

  f32x4 acc[4][4] = {};

  for (int k0 = 0; k0 < K; k0 += 32) {
    __syncthreads();                       // LDS safe to overwrite
    lds_load16(gA0 + k0, lAw0);
    lds_load16(gA1 + k0, lAw1);
    lds_load16(gB0 + k0, lBw0);
    lds_load16(gB1 + k0, lBw1);
    __syncthreads();                       // vmcnt(0) drain + barrier: tile ready
    bf16x8 af[4], bfr[4];
#pragma unroll
    for (int m = 0; m < 4; m++) af[m]  = *(const bf16x8*)(fA + m * 16 * 32);
#pragma unroll
    for (int n = 0; n < 4; n++) bfr[n] = *(const bf16x8*)(fB + n * 16 * 32);
#pragma unroll
    for (int m = 0; m < 4; m++)
#pragma unroll
      for (int n = 0; n < 4; n++)
        acc[m][n] = __builtin_amdgcn_mfma_f32_16x16x32_bf16(af[m], bfr[n], acc[m][n], 0, 0, 0);
  }

  // epilogue: C/D layout col=lane&15, row=(lane>>4)*4+j  [verified m89]
  const int fq = l >> 4;
#pragma unroll
  for (int m = 0; m < 4; m++) {
#pragma unroll
    for (int n = 0; n < 4; n++) {
      const int col = col0 + wc * 64 + n * 16 + fr;
#pragma unroll
      for (int j = 0; j < 4; j++) {
        const int rrow = row0 + wr * 64 + m * 16 + fq * 4 + j;
        const float val = acc[m][n][j];
        if constexpr (EPI == EPI_SCALE_F32) {
          float* Cp = (float*)Cv + (size_t)z * sCz;
          Cp[(size_t)rrow * ldc + col] = val * scale;
        } else if constexpr (EPI == EPI_BIAS_F32) {
          float* Cp = (float*)Cv;
          Cp[(size_t)rrow * ldc + col] = val + bias[col];
        } else if constexpr (EPI == EPI_BIAS_BF16) {
          bf16* Cp = (bf16*)Cv;
          Cp[(size_t)rrow * ldc + col] = (bf16)(val + bias[col]);
        } else if constexpr (EPI == EPI_BIAS_RELU) {
          bf16* Cp = (bf16*)Cv;
          Cp[(size_t)rrow * ldc + col] = (bf16)fmaxf(val + bias[col], 0.f);
        } else {  // EPI_RESID: C = acc + resid
          bf16* Cp = (bf16*)Cv + (size_t)z * sCz;
          const bf16* Rp = resid + (size_t)z * sRz;
          Cp[(size_t)rrow * ldc + col] = (bf16)(val + (float)Rp[(size_t)rrow * ldc + col]);
        }
      }
    }
  }
}

__global__ __launch_bounds__(256)
void cast_f32_to_bf16(const float* __restrict__ in, bf16* __restrict__ out, int n8) {
  int i = blockIdx.x * 256 + threadIdx.x;
  if (i >= n8) return;
  const float4* p = (const float4*)in;
  float4 a = p[2 * i], b = p[2 * i + 1];
  bf16x8 o;
  o[0] = (bf16)a.x; o[1] = (bf16)a.y; o[2] = (bf16)a.z; o[3] = (bf16)a.w;
  o[4] = (bf16)b.x; o[5] = (bf16)b.y; o[6] = (bf16)b.z; o[7] = (bf16)b.w;
  ((bf16x8*)out)[i] = o;
}

// batched transpose: in (z, R x C) -> out (z, C x R); 64x64 tiles
__global__ __launch_bounds__(256)
void transpose_bf16(const bf16* __restrict__ in, bf16* __restrict__ out, int R, int C) {
  __shared__ bf16 t[64][72];
  const bf16* ib = in + (size_t)blockIdx.z * R * C;
  bf16* ob = out + (size_t)blockIdx.z * R * C;
  const int r0 = blockIdx.y * 64, c0 = blockIdx.x * 64;
  const int tid = threadIdx.x;
#pragma unroll
  for (int p = 0; p < 2; p++) {
    int r = p * 32 + tid / 8, cc = (tid % 8) * 8;
    bf16x8 vv = *(const bf16x8*)(ib + (size_t)(r0 + r) * C + c0 + cc);
#pragma unroll
    for (int j = 0; j < 8; j++) t[r][cc + j] = vv[j];
  }
  __syncthreads();
#pragma unroll
  for (int p = 0; p < 2; p++) {
    int r = p * 32 + tid / 8, cc = (tid % 8) * 8;
    bf16x8 o;
#pragma unroll
    for (int j = 0; j < 8; j++) o[j] = t[cc + j][r];
    *(bf16x8*)(ob + (size_t)(c0 + r) * R + r0 + cc) = o;
  }
}

// row softmax: S (nrows x 2048 f32) -> P (bf16), one block (256 thr) per row
__global__ __launch_bounds__(256)
void softmax_rows(const float* __restrict__ S, bf16* __restrict__ P) {
  const size_t row = blockIdx.x;
  const float4* sr = (const float4*)(S + row * 2048);
  const int t = threadIdx.x, wv = t >> 6, ln = t & 63;
  float4 a = sr[2 * t], b = sr[2 * t + 1];
  float v[8] = {a.x, a.y, a.z, a.w, b.x, b.y, b.z, b.w};
  float m = v[0];
#pragma unroll
  for (int j = 1; j < 8; j++) m = fmaxf(m, v[j]);
  for (int o = 32; o; o >>= 1) m = fmaxf(m, __shfl_xor(m, o));
  __shared__ float redm[4], reds[4];
  if (ln == 0) redm[wv] = m;
  __syncthreads();
  m = fmaxf(fmaxf(redm[0], redm[1]), fmaxf(redm[2], redm[3]));
  float e[8], s = 0.f;
#pragma unroll
  for (int j = 0; j < 8; j++) { e[j] = __expf(v[j] - m); s += e[j]; }
  for (int o = 32; o; o >>= 1) s += __shfl_xor(s, o);
  if (ln == 0) reds[wv] = s;
  __syncthreads();
  s = reds[0] + reds[1] + reds[2] + reds[3];
  const float inv = 1.f / s;
  bf16x8 o8;
#pragma unroll
  for (int j = 0; j < 8; j++) o8[j] = (bf16)(e[j] * inv);
  ((bf16x8*)(P + row * 2048))[t] = o8;
}

extern "C" void kernel_launch(void* const* d_in, const int* in_sizes, int n_in,
                              void* d_out, int out_size, void* d_ws, size_t ws_size,
                              hipStream_t stream) {
  const float* x  = (const float*)d_in[0];
  const float* w1 = (const float*)d_in[1];
  const float* b1 = (const float*)d_in[2];
  const float* w2 = (const float*)d_in[3];
  const float* b2 = (const float*)d_in[4];
  const float* wq = (const float*)d_in[5];
  const float* bq = (const float*)d_in[6];
  const float* wk = (const float*)d_in[7];
  const float* bk = (const float*)d_in[8];
  const float* wv = (const float*)d_in[9];
  const float* bv = (const float*)d_in[10];
  const float* wo = (const float*)d_in[11];
  const float* bo = (const float*)d_in[12];
  float* out = (float*)d_out;

  char* ws = (char*)d_ws;
  const size_t MB = 1024ull * 1024ull;
  if (ws_size < 144 * MB) return;  // workspace layout needs 144 MB

  // persistent bf16 weights
  bf16* w1b = (bf16*)(ws + 0 * MB);    // 4 MB
  bf16* w2b = (bf16*)(ws + 4 * MB);    // 4 MB
  bf16* wqb = (bf16*)(ws + 8 * MB);    // 2 MB
  bf16* wkb = (bf16*)(ws + 10 * MB);   // 2 MB
  bf16* wvb = (bf16*)(ws + 12 * MB);   // 2 MB
  bf16* wob = (bf16*)(ws + 14 * MB);   // 2 MB
  // region A (16..80 MB): xb, h1, h  -> later S (f32, 64MB) -> later ctx (16MB)
  bf16* xb  = (bf16*)(ws + 16 * MB);   // 16 MB, dead after GEMM1
  bf16* h1  = (bf16*)(ws + 32 * MB);   // 32 MB, dead after GEMM2
  bf16* h   = (bf16*)(ws + 64 * MB);   // 16 MB, dead after QKV
  float* S  = (float*)(ws + 16 * MB);  // 64 MB, written step6, dead after softmax
  bf16* ctxb= (bf16*)(ws + 16 * MB);   // 16 MB, written step8
  // v / vT
  bf16* vb  = (bf16*)(ws + 80 * MB);   // 16 MB
  bf16* vT  = (bf16*)(ws + 96 * MB);   // 16 MB
  // region B (112..144 MB): q,k -> later P
  bf16* qb  = (bf16*)(ws + 112 * MB);  // 16 MB, dead after scores
  bf16* kb  = (bf16*)(ws + 128 * MB);  // 16 MB, dead after scores
  bf16* P   = (bf16*)(ws + 112 * MB);  // 32 MB, written by softmax

  // ---- casts to bf16 ----
  cast_f32_to_bf16<<<4096, 256, 0, stream>>>(x,  xb,  8192 * 1024 / 8);
  cast_f32_to_bf16<<<1024, 256, 0, stream>>>(w1, w1b, 2048 * 1024 / 8);
  cast_f32_to_bf16<<<1024, 256, 0, stream>>>(w2, w2b, 1024 * 2048 / 8);
  cast_f32_to_bf16<<<512, 256, 0, stream>>>(wq, wqb, 1024 * 1024 / 8);
  cast_f32_to_bf16<<<512, 256, 0, stream>>>(wk, wkb, 1024 * 1024 / 8);
  cast_f32_to_bf16<<<512, 256, 0, stream>>>(wv, wvb, 1024 * 1024 / 8);
  cast_f32_to_bf16<<<512, 256, 0, stream>>>(wo, wob, 1024 * 1024 / 8);

  // ---- 1: h1 = relu(x @ w1^T + b1)   M=8192 N=2048 K=1024
  gemm_bt<EPI_BIAS_RELU><<<dim3(16, 64, 1), 256, 0, stream>>>(
      xb, w1b, h1, b1, nullptr, 1024, 1024, 1024, 2048, 0, 0, 0, 0, 0.f);
  // ---- 2: h = relu(h1 @ w2^T + b2)   M=8192 N=1024 K=2048
  gemm_bt<EPI_BIAS_RELU><<<dim3(8, 64, 1), 256, 0, stream>>>(
      h1, w2b, h, b2, nullptr, 2048, 2048, 2048, 1024, 0, 0, 0, 0, 0.f);
  // ---- 3-5: q,k,v = h @ w{q,k,v}^T + b   M=8192 N=1024 K=1024
  gemm_bt<EPI_BIAS_BF16><<<dim3(8, 64, 1), 256, 0, stream>>>(
      h, wqb, qb, bq, nullptr, 1024, 1024, 1024, 1024, 0, 0, 0, 0, 0.f);
  gemm_bt<EPI_BIAS_BF16><<<dim3(8, 64, 1), 256, 0, stream>>>(
      h, wkb, kb, bk, nullptr, 1024, 1024, 1024, 1024, 0, 0, 0, 0, 0.f);
  gemm_bt<EPI_BIAS_BF16><<<dim3(8, 64, 1), 256, 0, stream>>>(
      h, wvb, vb, bv, nullptr, 1024, 1024, 1024, 1024, 0, 0, 0, 0, 0.f);
  // ---- v^T per batch (2048x1024 -> 1024x2048)
  transpose_bf16<<<dim3(16, 32, 4), 256, 0, stream>>>(vb, vT, 2048, 1024);
  // ---- 6: S = (q @ k^T) / 32, batched z=4   M=2048 N=2048 K=1024
  gemm_bt<EPI_SCALE_F32><<<dim3(16, 16, 4), 256, 0, stream>>>(
      qb, kb, S, nullptr, nullptr, 1024, 1024, 1024, 2048,
      2048LL * 1024, 2048LL * 1024, 2048LL * 2048, 0, 0.03125f);
  // ---- 7: P = softmax_rows(S), bf16
  softmax_rows<<<8192, 256, 0, stream>>>(S, P);
  // ---- 8: ctx = P @ vT^T + v, batched   M=2048 N=1024 K=2048
  gemm_bt<EPI_RESID><<<dim3(8, 16, 4), 256, 0, stream>>>(
      P, vT, ctxb, nullptr, vb, 2048, 2048, 2048, 1024,
      2048LL * 2048, 1024LL * 2048, 2048LL * 1024, 2048LL * 1024, 0.f);
  // ---- 9: out = ctx @ wo^T + bo (fp32)   M=8192 N=1024 K=1024
  gemm_bt<EPI_BIAS_F32><<<dim3(8, 64, 1), 256, 0, stream>>>(
      ctxb, wob, out, bo, nullptr, 1024, 1024, 1024, 1024, 0, 0, 0, 0, 0.f);
}

// Round 2
// 324.336 us; speedup vs baseline: 1.2672x; 1.2672x over previous
//
#include <hip/hip_runtime.h>
#include <hip/hip_bf16.h>

typedef __bf16 bf16;
typedef bf16 bf16x8 __attribute__((ext_vector_type(8)));
typedef float f32x4 __attribute__((ext_vector_type(4)));

#define EPI_BIAS_RELU  0
#define EPI_BIAS_BF16  1
#define EPI_PLAIN_BF16 2
#define EPI_RESID      3
#define EPI_BIAS_F32   4

__device__ __forceinline__ void lds_load16(const bf16* g, bf16* l) {
  __builtin_amdgcn_global_load_lds((__attribute__((address_space(1))) void*)g,
                                   (__attribute__((address_space(3))) void*)l,
                                   16, 0, 0);
}

// C = A (M x K, row-major, lda) * B^T (B is N x K row-major, ldb), epilogue fused.
// 128x128 tile, BK=64, double-buffered LDS (1 barrier per K-step), XOR-swizzled
// LDS layout (swizzle applied on the global source so global_load_lds stays linear).
template<int EPI>
__global__ __launch_bounds__(256)
void gemm_bt(const bf16* __restrict__ A, const bf16* __restrict__ B,
             void* __restrict__ Cv, const float* __restrict__ bias,
             const bf16* __restrict__ resid,
             int K, int lda, int ldb, int ldc,
             long long sAz, long long sBz, long long sCz, long long sRz)
{
  __shared__ __align__(16) bf16 lA[2][128 * 64];
  __shared__ __align__(16) bf16 lB[2][128 * 64];
  const int z = blockIdx.z;
  const bf16* Ab = A + (size_t)z * sAz;
  const bf16* Bb = B + (size_t)z * sBz;
  const int row0 = blockIdx.y * 128, col0 = blockIdx.x * 128;
  const int tid = threadIdx.x, w = tid >> 6, l = tid & 63;
  const int wr = w >> 1, wc = w & 1;

  // staging: wave w covers rows [w*32, w*32+32) in 4 chunks of 8 rows.
  // lane l -> row offset l>>3, swizzled 16B col-block (l&7)^(l>>3) so that the
  // linear LDS write lands data at swizzled position (rule #21 both-sides).
  const int srow = l >> 3;
  const int scb  = (l & 7) ^ srow;
  const bf16* gA = Ab + (size_t)(row0 + w * 32 + srow) * lda + scb * 8;
  const bf16* gB = Bb + (size_t)(col0 + w * 32 + srow) * ldb + scb * 8;

  const int fr = l & 15, fq = l >> 4;
  const int sw = fr & 7;  // row-dependent XOR for fragment reads

  f32x4 acc[4][4] = {};

  auto stage = [&](int buf, int k0) {
#pragma unroll
    for (int j = 0; j < 4; j++)
      lds_load16(gA + (size_t)(j * 8) * lda + k0, &lA[buf][(w * 32 + j * 8) * 64]);
#pragma unroll
    for (int j = 0; j < 4; j++)
      lds_load16(gB + (size_t)(j * 8) * ldb + k0, &lB[buf][(w * 32 + j * 8) * 64]);
  };

  auto compute = [&](int buf) {
    bf16x8 a0[4], a1[4], b0[4], b1[4];
#pragma unroll
    for (int m = 0; m < 4; m++) {
      const bf16* base = &lA[buf][(wr * 64 + m * 16 + fr) * 64];
      a0[m] = *(const bf16x8*)(base + ((fq)     ^ sw) * 8);
      a1[m] = *(const bf16x8*)(base + ((4 + fq) ^ sw) * 8);
    }
#pragma unroll
    for (int n = 0; n < 4; n++) {
      const bf16* base = &lB[buf][(wc * 64 + n * 16 + fr) * 64];
      b0[n] = *(const bf16x8*)(base + ((fq)     ^ sw) * 8);
      b1[n] = *(const bf16x8*)(base + ((4 + fq) ^ sw) * 8);
    }
#pragma unroll
    for (int m = 0; m < 4; m++)
#pragma unroll
      for (int n = 0; n < 4; n++)
        acc[m][n] = __builtin_amdgcn_mfma_f32_16x16x32_bf16(a0[m], b0[n], acc[m][n], 0, 0, 0);
#pragma unroll
    for (int m = 0; m < 4; m++)
#pragma unroll
      for (int n = 0; n < 4; n++)
        acc[m][n] = __builtin_amdgcn_mfma_f32_16x16x32_bf16(a1[m], b1[n], acc[m][n], 0, 0, 0);
  };

  stage(0, 0);
  __syncthreads();                    // drain + barrier: tile 0 ready
  const int NT = K >> 6;
  int cur = 0;
  for (int t = 0; t < NT - 1; ++t) {
    stage(cur ^ 1, (t + 1) << 6);     // prefetch next tile (in flight over MFMA)
    compute(cur);
    __syncthreads();                  // vmcnt(0)+lgkmcnt(0) drain + barrier
    cur ^= 1;
  }
  compute(cur);

  // epilogue: C/D layout col=lane&15, row=(lane>>4)*4+j  [verified m89]
#pragma unroll
  for (int m = 0; m < 4; m++) {
#pragma unroll
    for (int n = 0; n < 4; n++) {
      const int col = col0 + wc * 64 + n * 16 + fr;
#pragma unroll
      for (int j = 0; j < 4; j++) {
        const int rrow = row0 + wr * 64 + m * 16 + fq * 4 + j;
        const float val = acc[m][n][j];
        if constexpr (EPI == EPI_PLAIN_BF16) {
          bf16* Cp = (bf16*)Cv + (size_t)z * sCz;
          Cp[(size_t)rrow * ldc + col] = (bf16)val;
        } else if constexpr (EPI == EPI_BIAS_F32) {
          float* Cp = (float*)Cv;
          Cp[(size_t)rrow * ldc + col] = val + bias[col];
        } else if constexpr (EPI == EPI_BIAS_BF16) {
          bf16* Cp = (bf16*)Cv;
          Cp[(size_t)rrow * ldc + col] = (bf16)(val + bias[col]);
        } else if constexpr (EPI == EPI_BIAS_RELU) {
          bf16* Cp = (bf16*)Cv;
          Cp[(size_t)rrow * ldc + col] = (bf16)fmaxf(val + bias[col], 0.f);
        } else {  // EPI_RESID: C = acc + resid
          bf16* Cp = (bf16*)Cv + (size_t)z * sCz;
          const bf16* Rp = resid + (size_t)z * sRz;
          Cp[(size_t)rrow * ldc + col] = (bf16)(val + (float)Rp[(size_t)rrow * ldc + col]);
        }
      }
    }
  }
}

__global__ __launch_bounds__(256)
void cast_f32_to_bf16(const float* __restrict__ in, bf16* __restrict__ out,
                      int n8, float scale) {
  int i = blockIdx.x * 256 + threadIdx.x;
  if (i >= n8) return;
  const float4* p = (const float4*)in;
  float4 a = p[2 * i], b = p[2 * i + 1];
  bf16x8 o;
  o[0] = (bf16)(a.x * scale); o[1] = (bf16)(a.y * scale);
  o[2] = (bf16)(a.z * scale); o[3] = (bf16)(a.w * scale);
  o[4] = (bf16)(b.x * scale); o[5] = (bf16)(b.y * scale);
  o[6] = (bf16)(b.z * scale); o[7] = (bf16)(b.w * scale);
  ((bf16x8*)out)[i] = o;
}

__global__ __launch_bounds__(256)
void pack_bias_qk(const float* __restrict__ bq, const float* __restrict__ bk,
                  float* __restrict__ o) {
  int i = blockIdx.x * 256 + threadIdx.x;  // 2048 threads
  o[i] = (i < 1024) ? bq[i] * 0.03125f : bk[i - 1024];
}

// batched transpose: in (z, R x C) -> out (z, C x R); 64x64 tiles
__global__ __launch_bounds__(256)
void transpose_bf16(const bf16* __restrict__ in, bf16* __restrict__ out, int R, int C) {
  __shared__ bf16 t[64][72];
  const bf16* ib = in + (size_t)blockIdx.z * R * C;
  bf16* ob = out + (size_t)blockIdx.z * R * C;
  const int r0 = blockIdx.y * 64, c0 = blockIdx.x * 64;
  const int tid = threadIdx.x;
#pragma unroll
  for (int p = 0; p < 2; p++) {
    int r = p * 32 + tid / 8, cc = (tid % 8) * 8;
    bf16x8 vv = *(const bf16x8*)(ib + (size_t)(r0 + r) * C + c0 + cc);
#pragma unroll
    for (int j = 0; j < 8; j++) t[r][cc + j] = vv[j];
  }
  __syncthreads();
#pragma unroll
  for (int p = 0; p < 2; p++) {
    int r = p * 32 + tid / 8, cc = (tid % 8) * 8;
    bf16x8 o;
#pragma unroll
    for (int j = 0; j < 8; j++) o[j] = t[cc + j][r];
    *(bf16x8*)(ob + (size_t)(c0 + r) * R + r0 + cc) = o;
  }
}

// row softmax: S (nrows x 2048 bf16) -> P (bf16), one block (256 thr) per row
__global__ __launch_bounds__(256)
void softmax_rows(const bf16* __restrict__ S, bf16* __restrict__ P) {
  const size_t row = blockIdx.x;
  const int t = threadIdx.x, wv = t >> 6, ln = t & 63;
  bf16x8 v8 = ((const bf16x8*)(S + row * 2048))[t];
  float v[8];
#pragma unroll
  for (int j = 0; j < 8; j++) v[j] = (float)v8[j];
  float m = v[0];
#pragma unroll
  for (int j = 1; j < 8; j++) m = fmaxf(m, v[j]);
  for (int o = 32; o; o >>= 1) m = fmaxf(m, __shfl_xor(m, o));
  __shared__ float redm[4], reds[4];
  if (ln == 0) redm[wv] = m;
  __syncthreads();
  m = fmaxf(fmaxf(redm[0], redm[1]), fmaxf(redm[2], redm[3]));
  float e[8], s = 0.f;
#pragma unroll
  for (int j = 0; j < 8; j++) { e[j] = __expf(v[j] - m); s += e[j]; }
  for (int o = 32; o; o >>= 1) s += __shfl_xor(s, o);
  if (ln == 0) reds[wv] = s;
  __syncthreads();
  s = reds[0] + reds[1] + reds[2] + reds[3];
  const float inv = 1.f / s;
  bf16x8 o8;
#pragma unroll
  for (int j = 0; j < 8; j++) o8[j] = (bf16)(e[j] * inv);
  ((bf16x8*)(P + row * 2048))[t] = o8;
}

extern "C" void kernel_launch(void* const* d_in, const int* in_sizes, int n_in,
                              void* d_out, int out_size, void* d_ws, size_t ws_size,
                              hipStream_t stream) {
  const float* x  = (const float*)d_in[0];
  const float* w1 = (const float*)d_in[1];
  const float* b1 = (const float*)d_in[2];
  const float* w2 = (const float*)d_in[3];
  const float* b2 = (const float*)d_in[4];
  const float* wq = (const float*)d_in[5];
  const float* bq = (const float*)d_in[6];
  const float* wk = (const float*)d_in[7];
  const float* bk = (const float*)d_in[8];
  const float* wv = (const float*)d_in[9];
  const float* bv = (const float*)d_in[10];
  const float* wo = (const float*)d_in[11];
  const float* bo = (const float*)d_in[12];
  float* out = (float*)d_out;

  char* ws = (char*)d_ws;
  const size_t MB = 1024ull * 1024ull;
  if (ws_size < 144 * MB) return;

  // weights / biases
  bf16* w1b  = (bf16*)(ws + 0 * MB);    // 4 MB
  bf16* w2b  = (bf16*)(ws + 4 * MB);    // 4 MB
  bf16* wqkb = (bf16*)(ws + 8 * MB);    // 4 MB: [2048][1024] = wq/32 ; wk
  bf16* wvb  = (bf16*)(ws + 12 * MB);   // 2 MB
  bf16* wob  = (bf16*)(ws + 14 * MB);   // 2 MB
  float* bqk = (float*)(ws + 16 * MB);  // 8 KB
  // activations (lifetime-aliased)
  bf16* xb  = (bf16*)(ws + 17 * MB);    // 16 MB, dead after G1
  bf16* h1  = (bf16*)(ws + 33 * MB);    // 32 MB, dead after G2
  bf16* h   = (bf16*)(ws + 65 * MB);    // 16 MB, dead after Gqk/Gv
  bf16* qk  = (bf16*)(ws + 81 * MB);    // 32 MB [8192][2048], dead after Gs
  bf16* vb  = (bf16*)(ws + 113 * MB);   // 16 MB, alive through Gpv (residual)
  bf16* vT  = (bf16*)(ws + 17 * MB);    // 16 MB over dead xb
  bf16* S   = (bf16*)(ws + 33 * MB);    // 32 MB over dead h1, dead after softmax
  bf16* P   = (bf16*)(ws + 65 * MB);    // 32 MB over dead h + dead qk head
  bf16* ctx = (bf16*)(ws + 33 * MB);    // 16 MB over dead S

  // ---- casts (scale for wq folds the 1/sqrt(1024) attention scale) ----
  cast_f32_to_bf16<<<4096, 256, 0, stream>>>(x,  xb,  8192 * 1024 / 8, 1.f);
  cast_f32_to_bf16<<<1024, 256, 0, stream>>>(w1, w1b, 2048 * 1024 / 8, 1.f);
  cast_f32_to_bf16<<<1024, 256, 0, stream>>>(w2, w2b, 1024 * 2048 / 8, 1.f);
  cast_f32_to_bf16<<<512, 256, 0, stream>>>(wq, wqkb,                 1024 * 1024 / 8, 0.03125f);
  cast_f32_to_bf16<<<512, 256, 0, stream>>>(wk, wqkb + 1024 * 1024,   1024 * 1024 / 8, 1.f);
  cast_f32_to_bf16<<<512, 256, 0, stream>>>(wv, wvb, 1024 * 1024 / 8, 1.f);
  cast_f32_to_bf16<<<512, 256, 0, stream>>>(wo, wob, 1024 * 1024 / 8, 1.f);
  pack_bias_qk<<<8, 256, 0, stream>>>(bq, bk, bqk);

  // ---- 1: h1 = relu(x @ w1^T + b1)   M=8192 N=2048 K=1024
  gemm_bt<EPI_BIAS_RELU><<<dim3(16, 64, 1), 256, 0, stream>>>(
      xb, w1b, h1, b1, nullptr, 1024, 1024, 1024, 2048, 0, 0, 0, 0);
  // ---- 2: h = relu(h1 @ w2^T + b2)   M=8192 N=1024 K=2048
  gemm_bt<EPI_BIAS_RELU><<<dim3(8, 64, 1), 256, 0, stream>>>(
      h1, w2b, h, b2, nullptr, 2048, 2048, 2048, 1024, 0, 0, 0, 0);
  // ---- 3: [q/32 | k] = h @ wqkb^T + bqk   M=8192 N=2048 K=1024
  gemm_bt<EPI_BIAS_BF16><<<dim3(16, 64, 1), 256, 0, stream>>>(
      h, wqkb, qk, bqk, nullptr, 1024, 1024, 1024, 2048, 0, 0, 0, 0);
  // ---- 4: v = h @ wv^T + bv   M=8192 N=1024 K=1024
  gemm_bt<EPI_BIAS_BF16><<<dim3(8, 64, 1), 256, 0, stream>>>(
      h, wvb, vb, bv, nullptr, 1024, 1024, 1024, 1024, 0, 0, 0, 0);
  // ---- v^T per batch (2048x1024 -> 1024x2048)
  transpose_bf16<<<dim3(16, 32, 4), 256, 0, stream>>>(vb, vT, 2048, 1024);
  // ---- 5: S = qhat @ k^T (scale pre-folded), batched z=4, bf16 out
  gemm_bt<EPI_PLAIN_BF16><<<dim3(16, 16, 4), 256, 0, stream>>>(
      qk, qk + 1024, S, nullptr, nullptr, 1024, 2048, 2048, 2048,
      2048LL * 2048, 2048LL * 2048, 2048LL * 2048, 0);
  // ---- 6: P = softmax_rows(S)
  softmax_rows<<<8192, 256, 0, stream>>>(S, P);
  // ---- 7: ctx = P @ vT^T + v, batched   M=2048 N=1024 K=2048
  gemm_bt<EPI_RESID><<<dim3(8, 16, 4), 256, 0, stream>>>(
      P, vT, ctx, nullptr, vb, 2048, 2048, 2048, 1024,
      2048LL * 2048, 1024LL * 2048, 2048LL * 1024, 2048LL * 1024);
  // ---- 8: out = ctx @ wo^T + bo (fp32)   M=8192 N=1024 K=1024
  gemm_bt<EPI_BIAS_F32><<<dim3(8, 64, 1), 256, 0, stream>>>(
      ctx, wob, out, bo, nullptr, 1024, 1024, 1024, 1024, 0, 0, 0, 0);
}

// Round 3
// 324.011 us; speedup vs baseline: 1.2684x; 1.0010x over previous
//
#include <hip/hip_runtime.h>
#include <hip/hip_bf16.h>

typedef __bf16 bf16;
typedef bf16 bf16x8 __attribute__((ext_vector_type(8)));
typedef float f32x4 __attribute__((ext_vector_type(4)));

#define EPI_BIAS_RELU  0
#define EPI_BIAS_BF16  1
#define EPI_PLAIN_BF16 2
#define EPI_RESID      3
#define EPI_BIAS_F32   4

__device__ __forceinline__ void lds_load16(const bf16* g, bf16* l) {
  __builtin_amdgcn_global_load_lds((__attribute__((address_space(1))) void*)g,
                                   (__attribute__((address_space(3))) void*)l,
                                   16, 0, 0);
}

// C = A (M x K, row-major) * B^T (B is N x K row-major), 8-phase 256-wide tile.
// 512 threads (8 waves), BK=64, double-buffered XOR-swizzled LDS, counted vmcnt.
// Phase schedule per K-tile t (buffers: t in cur, t+1 staging into nxt):
//   P0: ds_read A-half0+B-half0 | issue t+1 loads q2,q3 | bar | MFMA(0,0) | bar
//   P1: ds_read A-half1         | issue t+1 loads q4,q5 | bar | MFMA(1,0) | bar
//   P2: ds_read B-half1         | issue t+1 loads q6,q7 | bar | MFMA(1,1) | bar
//   P3: (regs held)             | issue t+2 loads q0,q1 | bar | MFMA(0,1) | vmcnt(2) | bar
// q<NBCH are B chunks, rest A chunks; t+2's q0,q1 write lB[cur] whose last read
// was P2 (done before P2's closing barrier) -> no race.
template<int EPI, int BN, int WARPS_M, int WARPS_N>
__global__ __launch_bounds__(512, 2)
void gemm8p(const bf16* __restrict__ A, const bf16* __restrict__ B,
            void* __restrict__ Cv, const float* __restrict__ bias,
            const bf16* __restrict__ resid,
            int K, int lda, int ldb, int ldc,
            long long sAz, long long sBz, long long sCz, long long sRz)
{
  constexpr int BM = 256, BK = 64;
  constexpr int WM = BM / WARPS_M, WN = BN / WARPS_N;
  constexpr int M_REP = WM / 16, N_REP = WN / 16;
  constexpr int MH = M_REP / 2, NH = N_REP / 2;
  constexpr int NBCH = BN / 64, TOT = NBCH + 4;

  __shared__ __align__(16) bf16 lA[2][BM * BK];
  __shared__ __align__(16) bf16 lB[2][BN * BK];

  const int z = blockIdx.z;
  const bf16* Ab = A + (size_t)z * sAz;
  const bf16* Bb = B + (size_t)z * sBz;
  const int row0 = blockIdx.y * BM, col0 = blockIdx.x * BN;
  const int tid = threadIdx.x, w = tid >> 6, l = tid & 63;
  const int wr = w / WARPS_N, wc = w % WARPS_N;

  // staging: chunk = 64 rows; wave w covers 8 rows (w*8 + l>>3), 16B col-block
  // (l&7)^(l>>3) pre-swizzled on the GLOBAL side; LDS dest stays linear.
  const int srow = l >> 3, scb = (l & 7) ^ srow;
  const bf16* gA = Ab + (size_t)(row0 + w * 8 + srow) * lda + scb * 8;
  const bf16* gB = Bb + (size_t)(col0 + w * 8 + srow) * ldb + scb * 8;

  auto issue = [&](int buf, int k0, int q) {
    if (q < NBCH)
      lds_load16(gB + (size_t)(q * 64) * ldb + k0, &lB[buf][(q * 64 + w * 8) * BK]);
    else {
      const int c = q - NBCH;
      lds_load16(gA + (size_t)(c * 64) * lda + k0, &lA[buf][(c * 64 + w * 8) * BK]);
    }
  };

  // fragment reads: row-dependent XOR swizzle (sw = fr&7), kblk = kk*4 + fq
  const int fr = l & 15, fq = l >> 4, sw = fr & 7;

  bf16x8 aR0[MH][2], aR1[MH][2], bR0[NH][2], bR1[NH][2];
  f32x4 acc[M_REP][N_REP] = {};

  auto readA = [&](bf16x8 (&dst)[MH][2], int buf, int half) {
#pragma unroll
    for (int mh = 0; mh < MH; mh++) {
      const bf16* base = &lA[buf][(wr * WM + (half * MH + mh) * 16 + fr) * BK];
#pragma unroll
      for (int kk = 0; kk < 2; kk++)
        dst[mh][kk] = *(const bf16x8*)(base + ((kk * 4 + fq) ^ sw) * 8);
    }
  };
  auto readB = [&](bf16x8 (&dst)[NH][2], int buf, int half) {
#pragma unroll
    for (int nh = 0; nh < NH; nh++) {
      const bf16* base = &lB[buf][(wc * WN + (half * NH + nh) * 16 + fr) * BK];
#pragma unroll
      for (int kk = 0; kk < 2; kk++)
        dst[nh][kk] = *(const bf16x8*)(base + ((kk * 4 + fq) ^ sw) * 8);
    }
  };
  auto quad = [&](const bf16x8 (&a)[MH][2], const bf16x8 (&b)[NH][2],
                  int mBase, int nBase) {
    __builtin_amdgcn_s_setprio(1);
#pragma unroll
    for (int mh = 0; mh < MH; mh++)
#pragma unroll
      for (int nh = 0; nh < NH; nh++)
#pragma unroll
        for (int kk = 0; kk < 2; kk++)
          acc[mBase + mh][nBase + nh] = __builtin_amdgcn_mfma_f32_16x16x32_bf16(
              a[mh][kk], b[nh][kk], acc[mBase + mh][nBase + nh], 0, 0, 0);
    __builtin_amdgcn_s_setprio(0);
  };

  const int NT = K >> 6;
  // prologue: full tile 0 + tile 1's first pair, counted wait
#pragma unroll
  for (int q = 0; q < TOT; q++) issue(0, 0, q);
  issue(1, BK, 0);
  issue(1, BK, 1);
  asm volatile("s_waitcnt vmcnt(2)" ::: "memory");
  __builtin_amdgcn_s_barrier();

  for (int t = 0; t < NT; t++) {
    const int cur = t & 1, nxt = cur ^ 1;
    const bool hasN1 = (t + 1 < NT), hasN2 = (t + 2 < NT);
    const int k1 = (t + 1) << 6, k2 = (t + 2) << 6;
    // P0
    readA(aR0, cur, 0);
    readB(bR0, cur, 0);
    if (hasN1) { issue(nxt, k1, 2); issue(nxt, k1, 3); }
    __builtin_amdgcn_s_barrier();
    asm volatile("s_waitcnt lgkmcnt(0)" ::: "memory");
    quad(aR0, bR0, 0, 0);
    __builtin_amdgcn_s_barrier();
    // P1
    readA(aR1, cur, 1);
    if (hasN1) { issue(nxt, k1, 4); issue(nxt, k1, 5); }
    __builtin_amdgcn_s_barrier();
    asm volatile("s_waitcnt lgkmcnt(0)" ::: "memory");
    quad(aR1, bR0, MH, 0);
    __builtin_amdgcn_s_barrier();
    // P2
    readB(bR1, cur, 1);
    if constexpr (TOT == 8) {
      if (hasN1) { issue(nxt, k1, 6); issue(nxt, k1, 7); }
    }
    __builtin_amdgcn_s_barrier();
    asm volatile("s_waitcnt lgkmcnt(0)" ::: "memory");
    quad(aR1, bR1, MH, NH);
    __builtin_amdgcn_s_barrier();
    // P3 (no ds_read: aR0/bR1 held in regs)
    if (hasN2) { issue(cur, k2, 0); issue(cur, k2, 1); }
    __builtin_amdgcn_s_barrier();
    quad(aR0, bR1, 0, NH);
    if (hasN1) {
      if (hasN2) asm volatile("s_waitcnt vmcnt(2)" ::: "memory");
      else       asm volatile("s_waitcnt vmcnt(0)" ::: "memory");
      __builtin_amdgcn_s_barrier();
    }
  }

  // epilogue: C/D layout col=lane&15, row=(lane>>4)*4+j  [verified m89]
#pragma unroll
  for (int m = 0; m < M_REP; m++) {
#pragma unroll
    for (int n = 0; n < N_REP; n++) {
      const int col = col0 + wc * WN + n * 16 + fr;
#pragma unroll
      for (int j = 0; j < 4; j++) {
        const int rrow = row0 + wr * WM + m * 16 + fq * 4 + j;
        const float val = acc[m][n][j];
        if constexpr (EPI == EPI_PLAIN_BF16) {
          bf16* Cp = (bf16*)Cv + (size_t)z * sCz;
          Cp[(size_t)rrow * ldc + col] = (bf16)val;
        } else if constexpr (EPI == EPI_BIAS_F32) {
          float* Cp = (float*)Cv;
          Cp[(size_t)rrow * ldc + col] = val + bias[col];
        } else if constexpr (EPI == EPI_BIAS_BF16) {
          bf16* Cp = (bf16*)Cv;
          Cp[(size_t)rrow * ldc + col] = (bf16)(val + bias[col]);
        } else if constexpr (EPI == EPI_BIAS_RELU) {
          bf16* Cp = (bf16*)Cv;
          Cp[(size_t)rrow * ldc + col] = (bf16)fmaxf(val + bias[col], 0.f);
        } else {  // EPI_RESID
          bf16* Cp = (bf16*)Cv + (size_t)z * sCz;
          const bf16* Rp = resid + (size_t)z * sRz;
          Cp[(size_t)rrow * ldc + col] = (bf16)(val + (float)Rp[(size_t)rrow * ldc + col]);
        }
      }
    }
  }
}

__global__ __launch_bounds__(256)
void cast_f32_to_bf16(const float* __restrict__ in, bf16* __restrict__ out,
                      int n8, float scale) {
  int i = blockIdx.x * 256 + threadIdx.x;
  if (i >= n8) return;
  const float4* p = (const float4*)in;
  float4 a = p[2 * i], b = p[2 * i + 1];
  bf16x8 o;
  o[0] = (bf16)(a.x * scale); o[1] = (bf16)(a.y * scale);
  o[2] = (bf16)(a.z * scale); o[3] = (bf16)(a.w * scale);
  o[4] = (bf16)(b.x * scale); o[5] = (bf16)(b.y * scale);
  o[6] = (bf16)(b.z * scale); o[7] = (bf16)(b.w * scale);
  ((bf16x8*)out)[i] = o;
}

__global__ __launch_bounds__(256)
void pack_bias_qk(const float* __restrict__ bq, const float* __restrict__ bk,
                  float* __restrict__ o) {
  int i = blockIdx.x * 256 + threadIdx.x;  // 2048 threads
  o[i] = (i < 1024) ? bq[i] * 0.03125f : bk[i - 1024];
}

// batched transpose: in (z, R x C) -> out (z, C x R); 64x64 tiles
__global__ __launch_bounds__(256)
void transpose_bf16(const bf16* __restrict__ in, bf16* __restrict__ out, int R, int C) {
  __shared__ bf16 t[64][72];
  const bf16* ib = in + (size_t)blockIdx.z * R * C;
  bf16* ob = out + (size_t)blockIdx.z * R * C;
  const int r0 = blockIdx.y * 64, c0 = blockIdx.x * 64;
  const int tid = threadIdx.x;
#pragma unroll
  for (int p = 0; p < 2; p++) {
    int r = p * 32 + tid / 8, cc = (tid % 8) * 8;
    bf16x8 vv = *(const bf16x8*)(ib + (size_t)(r0 + r) * C + c0 + cc);
#pragma unroll
    for (int j = 0; j < 8; j++) t[r][cc + j] = vv[j];
  }
  __syncthreads();
#pragma unroll
  for (int p = 0; p < 2; p++) {
    int r = p * 32 + tid / 8, cc = (tid % 8) * 8;
    bf16x8 o;
#pragma unroll
    for (int j = 0; j < 8; j++) o[j] = t[cc + j][r];
    *(bf16x8*)(ob + (size_t)(c0 + r) * R + r0 + cc) = o;
  }
}

// row softmax: S (nrows x 2048 bf16) -> P (bf16), one block (256 thr) per row
__global__ __launch_bounds__(256)
void softmax_rows(const bf16* __restrict__ S, bf16* __restrict__ P) {
  const size_t row = blockIdx.x;
  const int t = threadIdx.x, wv = t >> 6, ln = t & 63;
  bf16x8 v8 = ((const bf16x8*)(S + row * 2048))[t];
  float v[8];
#pragma unroll
  for (int j = 0; j < 8; j++) v[j] = (float)v8[j];
  float m = v[0];
#pragma unroll
  for (int j = 1; j < 8; j++) m = fmaxf(m, v[j]);
  for (int o = 32; o; o >>= 1) m = fmaxf(m, __shfl_xor(m, o));
  __shared__ float redm[4], reds[4];
  if (ln == 0) redm[wv] = m;
  __syncthreads();
  m = fmaxf(fmaxf(redm[0], redm[1]), fmaxf(redm[2], redm[3]));
  float e[8], s = 0.f;
#pragma unroll
  for (int j = 0; j < 8; j++) { e[j] = __expf(v[j] - m); s += e[j]; }
  for (int o = 32; o; o >>= 1) s += __shfl_xor(s, o);
  if (ln == 0) reds[wv] = s;
  __syncthreads();
  s = reds[0] + reds[1] + reds[2] + reds[3];
  const float inv = 1.f / s;
  bf16x8 o8;
#pragma unroll
  for (int j = 0; j < 8; j++) o8[j] = (bf16)(e[j] * inv);
  ((bf16x8*)(P + row * 2048))[t] = o8;
}

extern "C" void kernel_launch(void* const* d_in, const int* in_sizes, int n_in,
                              void* d_out, int out_size, void* d_ws, size_t ws_size,
                              hipStream_t stream) {
  const float* x  = (const float*)d_in[0];
  const float* w1 = (const float*)d_in[1];
  const float* b1 = (const float*)d_in[2];
  const float* w2 = (const float*)d_in[3];
  const float* b2 = (const float*)d_in[4];
  const float* wq = (const float*)d_in[5];
  const float* bq = (const float*)d_in[6];
  const float* wk = (const float*)d_in[7];
  const float* bk = (const float*)d_in[8];
  const float* wv = (const float*)d_in[9];
  const float* bv = (const float*)d_in[10];
  const float* wo = (const float*)d_in[11];
  const float* bo = (const float*)d_in[12];
  float* out = (float*)d_out;

  char* ws = (char*)d_ws;
  const size_t MB = 1024ull * 1024ull;
  if (ws_size < 144 * MB) return;

  // weights / biases
  bf16* w1b  = (bf16*)(ws + 0 * MB);    // 4 MB
  bf16* w2b  = (bf16*)(ws + 4 * MB);    // 4 MB
  bf16* wqkb = (bf16*)(ws + 8 * MB);    // 4 MB: [2048][1024] = wq/32 ; wk
  bf16* wvb  = (bf16*)(ws + 12 * MB);   // 2 MB
  bf16* wob  = (bf16*)(ws + 14 * MB);   // 2 MB
  float* bqk = (float*)(ws + 16 * MB);  // 8 KB
  // activations (lifetime-aliased)
  bf16* xb  = (bf16*)(ws + 17 * MB);    // 16 MB, dead after G1
  bf16* h1  = (bf16*)(ws + 33 * MB);    // 32 MB, dead after G2
  bf16* h   = (bf16*)(ws + 65 * MB);    // 16 MB, dead after Gqk/Gv
  bf16* qk  = (bf16*)(ws + 81 * MB);    // 32 MB [8192][2048], dead after Gs
  bf16* vb  = (bf16*)(ws + 113 * MB);   // 16 MB, alive through Gpv (residual)
  bf16* vT  = (bf16*)(ws + 17 * MB);    // 16 MB over dead xb
  bf16* S   = (bf16*)(ws + 33 * MB);    // 32 MB over dead h1, dead after softmax
  bf16* P   = (bf16*)(ws + 65 * MB);    // 32 MB over dead h + dead qk head
  bf16* ctx = (bf16*)(ws + 33 * MB);    // 16 MB over dead S

  // ---- casts (wq cast folds the 1/sqrt(1024) attention scale) ----
  cast_f32_to_bf16<<<4096, 256, 0, stream>>>(x,  xb,  8192 * 1024 / 8, 1.f);
  cast_f32_to_bf16<<<1024, 256, 0, stream>>>(w1, w1b, 2048 * 1024 / 8, 1.f);
  cast_f32_to_bf16<<<1024, 256, 0, stream>>>(w2, w2b, 1024 * 2048 / 8, 1.f);
  cast_f32_to_bf16<<<512, 256, 0, stream>>>(wq, wqkb,                 1024 * 1024 / 8, 0.03125f);
  cast_f32_to_bf16<<<512, 256, 0, stream>>>(wk, wqkb + 1024 * 1024,   1024 * 1024 / 8, 1.f);
  cast_f32_to_bf16<<<512, 256, 0, stream>>>(wv, wvb, 1024 * 1024 / 8, 1.f);
  cast_f32_to_bf16<<<512, 256, 0, stream>>>(wo, wob, 1024 * 1024 / 8, 1.f);
  pack_bias_qk<<<8, 256, 0, stream>>>(bq, bk, bqk);

  // ---- 1: h1 = relu(x @ w1^T + b1)   M=8192 N=2048 K=1024  [256x256]
  gemm8p<EPI_BIAS_RELU, 256, 2, 4><<<dim3(8, 32, 1), 512, 0, stream>>>(
      xb, w1b, h1, b1, nullptr, 1024, 1024, 1024, 2048, 0, 0, 0, 0);
  // ---- 2: h = relu(h1 @ w2^T + b2)   M=8192 N=1024 K=2048  [256x128]
  gemm8p<EPI_BIAS_RELU, 128, 4, 2><<<dim3(8, 32, 1), 512, 0, stream>>>(
      h1, w2b, h, b2, nullptr, 2048, 2048, 2048, 1024, 0, 0, 0, 0);
  // ---- 3: [q/32 | k] = h @ wqkb^T + bqk   M=8192 N=2048 K=1024  [256x256]
  gemm8p<EPI_BIAS_BF16, 256, 2, 4><<<dim3(8, 32, 1), 512, 0, stream>>>(
      h, wqkb, qk, bqk, nullptr, 1024, 1024, 1024, 2048, 0, 0, 0, 0);
  // ---- 4: v = h @ wv^T + bv   M=8192 N=1024 K=1024  [256x128]
  gemm8p<EPI_BIAS_BF16, 128, 4, 2><<<dim3(8, 32, 1), 512, 0, stream>>>(
      h, wvb, vb, bv, nullptr, 1024, 1024, 1024, 1024, 0, 0, 0, 0);
  // ---- v^T per batch (2048x1024 -> 1024x2048)
  transpose_bf16<<<dim3(16, 32, 4), 256, 0, stream>>>(vb, vT, 2048, 1024);
  // ---- 5: S = qhat @ k^T (scale pre-folded), batched z=4  [256x256]
  gemm8p<EPI_PLAIN_BF16, 256, 2, 4><<<dim3(8, 8, 4), 512, 0, stream>>>(
      qk, qk + 1024, S, nullptr, nullptr, 1024, 2048, 2048, 2048,
      2048LL * 2048, 2048LL * 2048, 2048LL * 2048, 0);
  // ---- 6: P = softmax_rows(S)
  softmax_rows<<<8192, 256, 0, stream>>>(S, P);
  // ---- 7: ctx = P @ vT^T + v, batched   M=2048 N=1024 K=2048  [256x128]
  gemm8p<EPI_RESID, 128, 4, 2><<<dim3(8, 8, 4), 512, 0, stream>>>(
      P, vT, ctx, nullptr, vb, 2048, 2048, 2048, 1024,
      2048LL * 2048, 1024LL * 2048, 2048LL * 1024, 2048LL * 1024);
  // ---- 8: out = ctx @ wo^T + bo (fp32)   M=8192 N=1024 K=1024  [256x128]
  gemm8p<EPI_BIAS_F32, 128, 4, 2><<<dim3(8, 32, 1), 512, 0, stream>>>(
      ctx, wob, out, bo, nullptr, 1024, 1024, 1024, 1024, 0, 0, 0, 0);
}

// Round 4
// 308.491 us; speedup vs baseline: 1.3322x; 1.0503x over previous
//
#include <hip/hip_runtime.h>
#include <hip/hip_bf16.h>

typedef __bf16 bf16;
typedef bf16 bf16x8 __attribute__((ext_vector_type(8)));
typedef float f32x4 __attribute__((ext_vector_type(4)));

#define EPI_BIAS_RELU  0
#define EPI_BIAS_BF16  1
#define EPI_PLAIN_BF16 2
#define EPI_RESID      3
#define EPI_BIAS_F32   4

__device__ __forceinline__ void lds_load16(const bf16* g, bf16* l) {
  __builtin_amdgcn_global_load_lds((__attribute__((address_space(1))) void*)g,
                                   (__attribute__((address_space(3))) void*)l,
                                   16, 0, 0);
}

template<int N> __device__ __forceinline__ void vmw() {
  if constexpr (N == 0) asm volatile("s_waitcnt vmcnt(0)" ::: "memory");
  else if constexpr (N == 2) asm volatile("s_waitcnt vmcnt(2)" ::: "memory");
  else if constexpr (N == 3) asm volatile("s_waitcnt vmcnt(3)" ::: "memory");
  else if constexpr (N == 4) asm volatile("s_waitcnt vmcnt(4)" ::: "memory");
  else if constexpr (N == 5) asm volatile("s_waitcnt vmcnt(5)" ::: "memory");
  else if constexpr (N == 6) asm volatile("s_waitcnt vmcnt(6)" ::: "memory");
}
__device__ __forceinline__ void barrier() { asm volatile("s_barrier" ::: "memory"); }

// C = A (M x K, row-major) * B^T (B is N x K row-major), fused epilogue.
// BM x 256 tile, BK=64, 8 waves (2M x 4N), double-buffered XOR-swizzled LDS.
// Derived-waits 4-phase pipeline, ONE barrier per phase:
//  reads:  P0: A-half0(t)        P1: A-half1(t)   P2: B-half1(t)+B-half0(t+1)  P3: -
//  issues: P0: A0(t+1)           P1: A1(t+1)      P2: B0(t+2)                  P3: B1(t+1)
//  vmcnt:  P0: LA+LB (forces A1(t), B0(t+1))      P1: 2LA (forces B1(t))
//          P3: LA+2LB (forces A0(t+1))            [tail: vmcnt(0)]
//  MFMA:   P0: Q(A0,B0)  P1: Q(A1,B0)  P2: Q(A1,B1)  P3: Q(A0,B1)
// Every ds_read is covered by a prior-phase vmcnt+barrier (2-3 phase cover);
// every LDS overwrite is >=4 barriers after the region's last read.
template<int EPI, int BM>
__global__ __launch_bounds__(512, 2)
void gemm8p(const bf16* __restrict__ A, const bf16* __restrict__ B,
            void* __restrict__ Cv, const float* __restrict__ bias,
            const bf16* __restrict__ resid,
            int K, int lda, int ldb, int ldc,
            long long sAz, long long sBz, long long sCz, long long sRz)
{
  constexpr int BN = 256, BK = 64;
  constexpr int WARPS_N = 4;
  constexpr int WM = BM / 2, WN = BN / WARPS_N;            // 2M x 4N waves
  constexpr int M_REP = WM / 16, N_REP = WN / 16;          // per-wave 16x16 tiles
  constexpr int MH = M_REP / 2, NH = N_REP / 2;            // half sizes
  constexpr int LA = BM / 128, LB = BN / 128;              // per-wave loads per half

  __shared__ __align__(16) bf16 lA[2][BM * BK];
  __shared__ __align__(16) bf16 lB[2][BN * BK];

  const int z = blockIdx.z;
  const bf16* Ab = A + (size_t)z * sAz;
  const bf16* Bb = B + (size_t)z * sBz;
  const int row0 = blockIdx.y * BM, col0 = blockIdx.x * BN;
  const int tid = threadIdx.x, w = tid >> 6, l = tid & 63;
  const int wr = w >> 2, wc = w & 3;

  // staging: 1KB chunk = 8 rows x 64 cols; lane l -> row l>>3, 16B col-block
  // (l&7)^(l>>3) pre-swizzled on the GLOBAL side; LDS dest stays linear (rule 21).
  const int srow = l >> 3, scb = (l & 7) ^ srow;
  const bf16* gA = Ab + (size_t)(row0 + w * 8 + srow) * lda + scb * 8;
  const bf16* gB = Bb + (size_t)(col0 + w * 8 + srow) * ldb + scb * 8;

  auto issueA = [&](int buf, int k0, int h) {
#pragma unroll
    for (int i = 0; i < LA; i++)
      lds_load16(gA + (size_t)(h * (BM / 2) + i * 64) * lda + k0,
                 &lA[buf][(h * (BM / 2) + i * 64 + w * 8) * BK]);
  };
  auto issueB = [&](int buf, int k0, int h) {
#pragma unroll
    for (int i = 0; i < LB; i++)
      lds_load16(gB + (size_t)(h * (BN / 2) + i * 64) * ldb + k0,
                 &lB[buf][(h * (BN / 2) + i * 64 + w * 8) * BK]);
  };

  // fragment reads: row-dependent XOR swizzle (sw = fr&7), kblk = kk*4+fq
  const int fr = l & 15, fq = l >> 4, sw = fr & 7;

  bf16x8 aA0[MH][2], aA1[MH][2], bB0[NH][2], bB1[NH][2];
  f32x4 acc[M_REP][N_REP] = {};

  auto readA = [&](bf16x8 (&dst)[MH][2], int buf, int h) {
#pragma unroll
    for (int mm = 0; mm < MH; mm++) {
      const int r = h * (BM / 2) + wr * (WM / 2) + mm * 16 + fr;
      const bf16* base = &lA[buf][r * BK];
#pragma unroll
      for (int kk = 0; kk < 2; kk++)
        dst[mm][kk] = *(const bf16x8*)(base + ((kk * 4 + fq) ^ sw) * 8);
    }
  };
  auto readB = [&](bf16x8 (&dst)[NH][2], int buf, int h) {
#pragma unroll
    for (int nn = 0; nn < NH; nn++) {
      const int r = h * (BN / 2) + wc * (WN / 2) + nn * 16 + fr;
      const bf16* base = &lB[buf][r * BK];
#pragma unroll
      for (int kk = 0; kk < 2; kk++)
        dst[nn][kk] = *(const bf16x8*)(base + ((kk * 4 + fq) ^ sw) * 8);
    }
  };
  auto quad = [&](const bf16x8 (&a)[MH][2], const bf16x8 (&b)[NH][2],
                  int mBase, int nBase) {
    __builtin_amdgcn_s_setprio(1);
#pragma unroll
    for (int mh = 0; mh < MH; mh++)
#pragma unroll
      for (int nh = 0; nh < NH; nh++)
#pragma unroll
        for (int kk = 0; kk < 2; kk++)
          acc[mBase + mh][nBase + nh] = __builtin_amdgcn_mfma_f32_16x16x32_bf16(
              a[mh][kk], b[nh][kk], acc[mBase + mh][nBase + nh], 0, 0, 0);
    __builtin_amdgcn_s_setprio(0);
  };

  const int NT = K / BK;
  // prologue: tile0 fully + B0(1); force all but {B1(0), B0(1)}; pre-read B0(0)
  issueA(0, 0, 0); issueA(0, 0, 1);
  issueB(0, 0, 0); issueB(0, 0, 1);
  issueB(1, BK, 0);
  vmw<2 * LB>();
  barrier();
  readB(bB0, 0, 0);

  for (int t = 0; t < NT; t++) {
    const int cur = t & 1, nxt = cur ^ 1;
    const bool n1 = (t + 1 < NT), n2 = (t + 2 < NT);
    const int k1 = (t + 1) * BK, k2 = (t + 2) * BK;
    // P0
    readA(aA0, cur, 0);
    if (n1) issueA(nxt, k1, 0);
    if (n2) vmw<LA + LB>(); else vmw<0>();
    barrier();
    quad(aA0, bB0, 0, 0);
    // P1
    readA(aA1, cur, 1);
    if (n1) issueA(nxt, k1, 1);
    if (n2) vmw<2 * LA>(); else vmw<0>();
    barrier();
    quad(aA1, bB0, MH, 0);
    // P2
    readB(bB1, cur, 1);
    if (n1) readB(bB0, nxt, 0);
    if (n2) issueB(cur, k2, 0);
    barrier();
    quad(aA1, bB1, MH, NH);
    // P3
    if (n1) issueB(nxt, k1, 1);
    if (n2) vmw<LA + 2 * LB>(); else vmw<0>();
    barrier();
    quad(aA0, bB1, 0, NH);
  }

  // epilogue: C/D layout col=lane&15, row=(lane>>4)*4+j  [verified m89]
#pragma unroll
  for (int m = 0; m < M_REP; m++) {
#pragma unroll
    for (int n = 0; n < N_REP; n++) {
      const int col = col0 + (n / NH) * (BN / 2) + wc * (WN / 2) + (n % NH) * 16 + fr;
#pragma unroll
      for (int j = 0; j < 4; j++) {
        const int rrow = row0 + (m / MH) * (BM / 2) + wr * (WM / 2) + (m % MH) * 16 + fq * 4 + j;
        const float val = acc[m][n][j];
        if constexpr (EPI == EPI_PLAIN_BF16) {
          bf16* Cp = (bf16*)Cv + (size_t)z * sCz;
          Cp[(size_t)rrow * ldc + col] = (bf16)val;
        } else if constexpr (EPI == EPI_BIAS_F32) {
          float* Cp = (float*)Cv;
          Cp[(size_t)rrow * ldc + col] = val + bias[col];
        } else if constexpr (EPI == EPI_BIAS_BF16) {
          bf16* Cp = (bf16*)Cv;
          Cp[(size_t)rrow * ldc + col] = (bf16)(val + bias[col]);
        } else if constexpr (EPI == EPI_BIAS_RELU) {
          bf16* Cp = (bf16*)Cv;
          Cp[(size_t)rrow * ldc + col] = (bf16)fmaxf(val + bias[col], 0.f);
        } else {  // EPI_RESID
          bf16* Cp = (bf16*)Cv + (size_t)z * sCz;
          const bf16* Rp = resid + (size_t)z * sRz;
          Cp[(size_t)rrow * ldc + col] = (bf16)(val + (float)Rp[(size_t)rrow * ldc + col]);
        }
      }
    }
  }
}

__global__ __launch_bounds__(256)
void cast_f32_to_bf16(const float* __restrict__ in, bf16* __restrict__ out,
                      int n8, float scale) {
  int i = blockIdx.x * 256 + threadIdx.x;
  if (i >= n8) return;
  const float4* p = (const float4*)in;
  float4 a = p[2 * i], b = p[2 * i + 1];
  bf16x8 o;
  o[0] = (bf16)(a.x * scale); o[1] = (bf16)(a.y * scale);
  o[2] = (bf16)(a.z * scale); o[3] = (bf16)(a.w * scale);
  o[4] = (bf16)(b.x * scale); o[5] = (bf16)(b.y * scale);
  o[6] = (bf16)(b.z * scale); o[7] = (bf16)(b.w * scale);
  ((bf16x8*)out)[i] = o;
}

__global__ __launch_bounds__(256)
void pack_bias_qk(const float* __restrict__ bq, const float* __restrict__ bk,
                  float* __restrict__ o) {
  int i = blockIdx.x * 256 + threadIdx.x;  // 2048 threads
  o[i] = (i < 1024) ? bq[i] * 0.03125f : bk[i - 1024];
}

// batched transpose: in (z, R x C) -> out (z, C x R); 64x64 tiles
__global__ __launch_bounds__(256)
void transpose_bf16(const bf16* __restrict__ in, bf16* __restrict__ out, int R, int C) {
  __shared__ bf16 t[64][72];
  const bf16* ib = in + (size_t)blockIdx.z * R * C;
  bf16* ob = out + (size_t)blockIdx.z * R * C;
  const int r0 = blockIdx.y * 64, c0 = blockIdx.x * 64;
  const int tid = threadIdx.x;
#pragma unroll
  for (int p = 0; p < 2; p++) {
    int r = p * 32 + tid / 8, cc = (tid % 8) * 8;
    bf16x8 vv = *(const bf16x8*)(ib + (size_t)(r0 + r) * C + c0 + cc);
#pragma unroll
    for (int j = 0; j < 8; j++) t[r][cc + j] = vv[j];
  }
  __syncthreads();
#pragma unroll
  for (int p = 0; p < 2; p++) {
    int r = p * 32 + tid / 8, cc = (tid % 8) * 8;
    bf16x8 o;
#pragma unroll
    for (int j = 0; j < 8; j++) o[j] = t[cc + j][r];
    *(bf16x8*)(ob + (size_t)(c0 + r) * R + r0 + cc) = o;
  }
}

// row softmax: S (nrows x 2048 bf16) -> P (bf16), one block (256 thr) per row
__global__ __launch_bounds__(256)
void softmax_rows(const bf16* __restrict__ S, bf16* __restrict__ P) {
  const size_t row = blockIdx.x;
  const int t = threadIdx.x, wv = t >> 6, ln = t & 63;
  bf16x8 v8 = ((const bf16x8*)(S + row * 2048))[t];
  float v[8];
#pragma unroll
  for (int j = 0; j < 8; j++) v[j] = (float)v8[j];
  float m = v[0];
#pragma unroll
  for (int j = 1; j < 8; j++) m = fmaxf(m, v[j]);
  for (int o = 32; o; o >>= 1) m = fmaxf(m, __shfl_xor(m, o));
  __shared__ float redm[4], reds[4];
  if (ln == 0) redm[wv] = m;
  __syncthreads();
  m = fmaxf(fmaxf(redm[0], redm[1]), fmaxf(redm[2], redm[3]));
  float e[8], s = 0.f;
#pragma unroll
  for (int j = 0; j < 8; j++) { e[j] = __expf(v[j] - m); s += e[j]; }
  for (int o = 32; o; o >>= 1) s += __shfl_xor(s, o);
  if (ln == 0) reds[wv] = s;
  __syncthreads();
  s = reds[0] + reds[1] + reds[2] + reds[3];
  const float inv = 1.f / s;
  bf16x8 o8;
#pragma unroll
  for (int j = 0; j < 8; j++) o8[j] = (bf16)(e[j] * inv);
  ((bf16x8*)(P + row * 2048))[t] = o8;
}

extern "C" void kernel_launch(void* const* d_in, const int* in_sizes, int n_in,
                              void* d_out, int out_size, void* d_ws, size_t ws_size,
                              hipStream_t stream) {
  const float* x  = (const float*)d_in[0];
  const float* w1 = (const float*)d_in[1];
  const float* b1 = (const float*)d_in[2];
  const float* w2 = (const float*)d_in[3];
  const float* b2 = (const float*)d_in[4];
  const float* wq = (const float*)d_in[5];
  const float* bq = (const float*)d_in[6];
  const float* wk = (const float*)d_in[7];
  const float* bk = (const float*)d_in[8];
  const float* wv = (const float*)d_in[9];
  const float* bv = (const float*)d_in[10];
  const float* wo = (const float*)d_in[11];
  const float* bo = (const float*)d_in[12];
  float* out = (float*)d_out;

  char* ws = (char*)d_ws;
  const size_t MB = 1024ull * 1024ull;
  if (ws_size < 144 * MB) return;

  // weights / biases
  bf16* w1b  = (bf16*)(ws + 0 * MB);    // 4 MB
  bf16* w2b  = (bf16*)(ws + 4 * MB);    // 4 MB
  bf16* wqkb = (bf16*)(ws + 8 * MB);    // 4 MB: [2048][1024] = wq/32 ; wk
  bf16* wvb  = (bf16*)(ws + 12 * MB);   // 2 MB
  bf16* wob  = (bf16*)(ws + 14 * MB);   // 2 MB
  float* bqk = (float*)(ws + 16 * MB);  // 8 KB
  // activations (lifetime-aliased)
  bf16* xb  = (bf16*)(ws + 17 * MB);    // 16 MB, dead after G1
  bf16* h1  = (bf16*)(ws + 33 * MB);    // 32 MB, dead after G2
  bf16* h   = (bf16*)(ws + 65 * MB);    // 16 MB, dead after Gqk/Gv
  bf16* qk  = (bf16*)(ws + 81 * MB);    // 32 MB [8192][2048], dead after Gs
  bf16* vb  = (bf16*)(ws + 113 * MB);   // 16 MB, alive through Gpv (residual)
  bf16* vT  = (bf16*)(ws + 17 * MB);    // 16 MB over dead xb
  bf16* S   = (bf16*)(ws + 33 * MB);    // 32 MB over dead h1, dead after softmax
  bf16* P   = (bf16*)(ws + 65 * MB);    // 32 MB over dead h + dead qk head
  bf16* ctx = (bf16*)(ws + 33 * MB);    // 16 MB over dead S

  // ---- casts (wq cast folds the 1/sqrt(1024) attention scale) ----
  cast_f32_to_bf16<<<4096, 256, 0, stream>>>(x,  xb,  8192 * 1024 / 8, 1.f);
  cast_f32_to_bf16<<<1024, 256, 0, stream>>>(w1, w1b, 2048 * 1024 / 8, 1.f);
  cast_f32_to_bf16<<<1024, 256, 0, stream>>>(w2, w2b, 1024 * 2048 / 8, 1.f);
  cast_f32_to_bf16<<<512, 256, 0, stream>>>(wq, wqkb,                 1024 * 1024 / 8, 0.03125f);
  cast_f32_to_bf16<<<512, 256, 0, stream>>>(wk, wqkb + 1024 * 1024,   1024 * 1024 / 8, 1.f);
  cast_f32_to_bf16<<<512, 256, 0, stream>>>(wv, wvb, 1024 * 1024 / 8, 1.f);
  cast_f32_to_bf16<<<512, 256, 0, stream>>>(wo, wob, 1024 * 1024 / 8, 1.f);
  pack_bias_qk<<<8, 256, 0, stream>>>(bq, bk, bqk);

  // ---- 1: h1 = relu(x @ w1^T + b1)   M=8192 N=2048 K=1024  [256x256]
  gemm8p<EPI_BIAS_RELU, 256><<<dim3(8, 32, 1), 512, 0, stream>>>(
      xb, w1b, h1, b1, nullptr, 1024, 1024, 1024, 2048, 0, 0, 0, 0);
  // ---- 2: h = relu(h1 @ w2^T + b2)   M=8192 N=1024 K=2048  [128x256]
  gemm8p<EPI_BIAS_RELU, 128><<<dim3(4, 64, 1), 512, 0, stream>>>(
      h1, w2b, h, b2, nullptr, 2048, 2048, 2048, 1024, 0, 0, 0, 0);
  // ---- 3: [q/32 | k] = h @ wqkb^T + bqk   M=8192 N=2048 K=1024  [256x256]
  gemm8p<EPI_BIAS_BF16, 256><<<dim3(8, 32, 1), 512, 0, stream>>>(
      h, wqkb, qk, bqk, nullptr, 1024, 1024, 1024, 2048, 0, 0, 0, 0);
  // ---- 4: v = h @ wv^T + bv   M=8192 N=1024 K=1024  [128x256]
  gemm8p<EPI_BIAS_BF16, 128><<<dim3(4, 64, 1), 512, 0, stream>>>(
      h, wvb, vb, bv, nullptr, 1024, 1024, 1024, 1024, 0, 0, 0, 0);
  // ---- v^T per batch (2048x1024 -> 1024x2048)
  transpose_bf16<<<dim3(16, 32, 4), 256, 0, stream>>>(vb, vT, 2048, 1024);
  // ---- 5: S = qhat @ k^T (scale pre-folded), batched z=4  [256x256]
  gemm8p<EPI_PLAIN_BF16, 256><<<dim3(8, 8, 4), 512, 0, stream>>>(
      qk, qk + 1024, S, nullptr, nullptr, 1024, 2048, 2048, 2048,
      2048LL * 2048, 2048LL * 2048, 2048LL * 2048, 0);
  // ---- 6: P = softmax_rows(S)
  softmax_rows<<<8192, 256, 0, stream>>>(S, P);
  // ---- 7: ctx = P @ vT^T + v, batched   M=2048 N=1024 K=2048  [128x256]
  gemm8p<EPI_RESID, 128><<<dim3(4, 16, 4), 512, 0, stream>>>(
      P, vT, ctx, nullptr, vb, 2048, 2048, 2048, 1024,
      2048LL * 2048, 1024LL * 2048, 2048LL * 1024, 2048LL * 1024);
  // ---- 8: out = ctx @ wo^T + bo (fp32)   M=8192 N=1024 K=1024  [128x256]
  gemm8p<EPI_BIAS_F32, 128><<<dim3(4, 64, 1), 512, 0, stream>>>(
      ctx, wob, out, bo, nullptr, 1024, 1024, 1024, 1024, 0, 0, 0, 0);
}

// Round 5
// 286.200 us; speedup vs baseline: 1.4360x; 1.0779x over previous
//
#include <hip/hip_runtime.h>
#include <hip/hip_bf16.h>

typedef __bf16 bf16;
typedef bf16 bf16x8 __attribute__((ext_vector_type(8)));
typedef float f32x4 __attribute__((ext_vector_type(4)));

#define EPI_BIAS_RELU  0
#define EPI_BIAS_BF16  1
#define EPI_PLAIN_BF16 2
#define EPI_RESID      3
#define EPI_BIAS_F32   4

__device__ __forceinline__ void lds_load16(const bf16* g, bf16* l) {
  __builtin_amdgcn_global_load_lds((__attribute__((address_space(1))) void*)g,
                                   (__attribute__((address_space(3))) void*)l,
                                   16, 0, 0);
}

template<int N> __device__ __forceinline__ void vmw() {
  if constexpr (N == 0) asm volatile("s_waitcnt vmcnt(0)" ::: "memory");
  else if constexpr (N == 4) asm volatile("s_waitcnt vmcnt(4)" ::: "memory");
  else if constexpr (N == 6) asm volatile("s_waitcnt vmcnt(6)" ::: "memory");
}
__device__ __forceinline__ void barrier() { asm volatile("s_barrier" ::: "memory"); }

// C = A (M x K, row-major) * B^T (B is N x K row-major), fused epilogue.
// m201-style 8-phase port: BM x 256 tile, BK=64, 8 waves (2M x 4N),
// double-buffered XOR-swizzled LDS, ONE counted vmcnt per K-tile.
//
// Half-tiles: A0,A1 (BM/2 rows each), B0,B1 (128 rows each). 4 phases/K-tile,
// each phase = {ds_read frags | stage 1 half | bar | MFMA quadrant | bar}.
// Stage table at tile t:  p0: B1(t+1)  p1: A0(t+2)  p2: B0(t+2)  p3: A1(t+2)
// -> every half staged 5-7 phases before its read. Single vmcnt<N3> at p3
// leaves only the newest 3 slots {A0,B0,A1}(t+2) outstanding; everything
// tile t+1 needs is forced. Drain vmcnt(0) at t+2>=NT (tail).
// Overwrite ledger: stage of X(t+2) issues >=2 barriers after last read of
// X(t) (reads at phase start complete before that phase's MFMA via
// compiler-inserted lgkmcnt; stage issued in a later phase). Race-free.
template<int EPI, int BM>
__global__ __launch_bounds__(512, 2)
void gemm8p(const bf16* __restrict__ A, const bf16* __restrict__ B,
            void* __restrict__ Cv, const float* __restrict__ bias,
            const bf16* __restrict__ resid,
            int K, int lda, int ldb, int ldc,
            long long sAz, long long sBz, long long sCz, long long sRz)
{
  constexpr int BN = 256, BK = 64;
  constexpr int WM = BM / 2, WN = 64;            // 2M x 4N waves
  constexpr int M_REP = WM / 16, N_REP = 4;
  constexpr int MH = M_REP / 2, NH = 2;
  constexpr int LA = BM / 128, LB = 2;           // loads/wave per half-stage
  constexpr int N3 = LA + LB + LA;               // newest-3-slot load count

  __shared__ __align__(16) bf16 lA[2][BM * BK];
  __shared__ __align__(16) bf16 lB[2][BN * BK];

  // ---- bijective chunked XCD swizzle (nwg % 8 == 0 for all our grids) ----
  const int gx = gridDim.x, gy = gridDim.y;
  const int nwg = gx * gy * gridDim.z;
  int o = (blockIdx.z * gy + blockIdx.y) * gx + blockIdx.x;
  o = (o & 7) * (nwg >> 3) + (o >> 3);
  const int bx = o % gx;
  const int rem = o / gx;
  const int by = rem % gy;
  const int z = rem / gy;

  const bf16* Ab = A + (size_t)z * sAz;
  const bf16* Bb = B + (size_t)z * sBz;
  const int row0 = by * BM, col0 = bx * BN;
  const int tid = threadIdx.x, w = tid >> 6, l = tid & 63;
  const int wr = w >> 2, wc = w & 3;

  // staging: 1KB chunk = 8 rows x 64 cols; lane l -> row l>>3, 16B col-block
  // (l&7)^(l>>3) pre-swizzled on the GLOBAL side; LDS dest linear (rule 21).
  const int srow = l >> 3, scb = (l & 7) ^ srow;
  const bf16* gA = Ab + (size_t)(row0 + w * 8 + srow) * lda + scb * 8;
  const bf16* gB = Bb + (size_t)(col0 + w * 8 + srow) * ldb + scb * 8;

  auto issueA = [&](int buf, int k0, int h) {
#pragma unroll
    for (int i = 0; i < LA; i++)
      lds_load16(gA + (size_t)(h * (BM / 2) + i * 64) * lda + k0,
                 &lA[buf][(h * (BM / 2) + i * 64 + w * 8) * BK]);
  };
  auto issueB = [&](int buf, int k0, int h) {
#pragma unroll
    for (int i = 0; i < LB; i++)
      lds_load16(gB + (size_t)(h * 128 + i * 64) * ldb + k0,
                 &lB[buf][(h * 128 + i * 64 + w * 8) * BK]);
  };

  // fragment reads: row-dependent XOR swizzle (sw = fr&7), kblk = kk*4+fq
  const int fr = l & 15, fq = l >> 4, sw = fr & 7;

  bf16x8 aA0[MH][2], aA1[MH][2], bB0[NH][2], bB1[NH][2];
  f32x4 acc[M_REP][N_REP] = {};

  auto readA = [&](bf16x8 (&dst)[MH][2], int buf, int h) {
#pragma unroll
    for (int mm = 0; mm < MH; mm++) {
      const int r = h * (BM / 2) + wr * (WM / 2) + mm * 16 + fr;
      const bf16* base = &lA[buf][r * BK];
#pragma unroll
      for (int kk = 0; kk < 2; kk++)
        dst[mm][kk] = *(const bf16x8*)(base + ((kk * 4 + fq) ^ sw) * 8);
    }
  };
  auto readB = [&](bf16x8 (&dst)[NH][2], int buf, int h) {
#pragma unroll
    for (int nn = 0; nn < NH; nn++) {
      const int r = h * 128 + wc * 32 + nn * 16 + fr;
      const bf16* base = &lB[buf][r * BK];
#pragma unroll
      for (int kk = 0; kk < 2; kk++)
        dst[nn][kk] = *(const bf16x8*)(base + ((kk * 4 + fq) ^ sw) * 8);
    }
  };
  auto quad = [&](const bf16x8 (&a)[MH][2], const bf16x8 (&b)[NH][2],
                  int mBase, int nBase) {
    __builtin_amdgcn_s_setprio(1);
#pragma unroll
    for (int mh = 0; mh < MH; mh++)
#pragma unroll
      for (int nh = 0; nh < NH; nh++)
#pragma unroll
        for (int kk = 0; kk < 2; kk++)
          acc[mBase + mh][nBase + nh] = __builtin_amdgcn_mfma_f32_16x16x32_bf16(
              a[mh][kk], b[nh][kk], acc[mBase + mh][nBase + nh], 0, 0, 0);
    __builtin_amdgcn_s_setprio(0);
  };

  const int NT = K / BK;
  // prologue: full tile0 + tile1 minus B1(1); counted wait leaves tile1's
  // {A0,B0,A1} (= N3 loads) outstanding — the steady-state invariant at p0(0).
  issueA(0, 0, 0); issueB(0, 0, 0); issueA(0, 0, 1); issueB(0, 0, 1);
  issueA(1, BK, 0); issueB(1, BK, 0); issueA(1, BK, 1);
  vmw<N3>();
  barrier();

  for (int t = 0; t < NT; t++) {
    const int cur = t & 1, nxt = cur ^ 1;
    const bool s1 = (t + 1 < NT), s2 = (t + 2 < NT);
    const int k1 = (t + 1) * BK, k2 = (t + 2) * BK;
    // p0: read A0(t),B0(t) | stage B1(t+1)
    readA(aA0, cur, 0);
    readB(bB0, cur, 0);
    if (s1) issueB(nxt, k1, 1);
    barrier();
    quad(aA0, bB0, 0, 0);
    barrier();
    // p1: read A1(t) | stage A0(t+2)
    readA(aA1, cur, 1);
    if (s2) issueA(cur, k2, 0);
    barrier();
    quad(aA1, bB0, MH, 0);
    barrier();
    // p2: read B1(t) | stage B0(t+2)
    readB(bB1, cur, 1);
    if (s2) issueB(cur, k2, 0);
    barrier();
    quad(aA1, bB1, MH, NH);
    barrier();
    // p3: stage A1(t+2) | ONE counted vmcnt per K-tile
    if (s2) { issueA(cur, k2, 1); vmw<N3>(); }
    else vmw<0>();
    barrier();
    quad(aA0, bB1, 0, NH);
    barrier();
  }

  // epilogue: C/D layout col=lane&15, row=(lane>>4)*4+j  [verified m89]
#pragma unroll
  for (int m = 0; m < M_REP; m++) {
#pragma unroll
    for (int n = 0; n < N_REP; n++) {
      const int col = col0 + (n / NH) * 128 + wc * 32 + (n % NH) * 16 + fr;
#pragma unroll
      for (int j = 0; j < 4; j++) {
        const int rrow = row0 + (m / MH) * (BM / 2) + wr * (WM / 2) + (m % MH) * 16 + fq * 4 + j;
        const float val = acc[m][n][j];
        if constexpr (EPI == EPI_PLAIN_BF16) {
          bf16* Cp = (bf16*)Cv + (size_t)z * sCz;
          Cp[(size_t)rrow * ldc + col] = (bf16)val;
        } else if constexpr (EPI == EPI_BIAS_F32) {
          float* Cp = (float*)Cv;
          Cp[(size_t)rrow * ldc + col] = val + bias[col];
        } else if constexpr (EPI == EPI_BIAS_BF16) {
          bf16* Cp = (bf16*)Cv;
          Cp[(size_t)rrow * ldc + col] = (bf16)(val + bias[col]);
        } else if constexpr (EPI == EPI_BIAS_RELU) {
          bf16* Cp = (bf16*)Cv;
          Cp[(size_t)rrow * ldc + col] = (bf16)fmaxf(val + bias[col], 0.f);
        } else {  // EPI_RESID
          bf16* Cp = (bf16*)Cv + (size_t)z * sCz;
          const bf16* Rp = resid + (size_t)z * sRz;
          Cp[(size_t)rrow * ldc + col] = (bf16)(val + (float)Rp[(size_t)rrow * ldc + col]);
        }
      }
    }
  }
}

__global__ __launch_bounds__(256)
void cast_f32_to_bf16(const float* __restrict__ in, bf16* __restrict__ out,
                      int n8, float scale) {
  int i = blockIdx.x * 256 + threadIdx.x;
  if (i >= n8) return;
  const float4* p = (const float4*)in;
  float4 a = p[2 * i], b = p[2 * i + 1];
  bf16x8 o;
  o[0] = (bf16)(a.x * scale); o[1] = (bf16)(a.y * scale);
  o[2] = (bf16)(a.z * scale); o[3] = (bf16)(a.w * scale);
  o[4] = (bf16)(b.x * scale); o[5] = (bf16)(b.y * scale);
  o[6] = (bf16)(b.z * scale); o[7] = (bf16)(b.w * scale);
  ((bf16x8*)out)[i] = o;
}

__global__ __launch_bounds__(256)
void pack_bias_qk(const float* __restrict__ bq, const float* __restrict__ bk,
                  float* __restrict__ o) {
  int i = blockIdx.x * 256 + threadIdx.x;  // 2048 threads
  o[i] = (i < 1024) ? bq[i] * 0.03125f : bk[i - 1024];
}

// batched transpose: in (z, R x C) -> out (z, C x R); 64x64 tiles
__global__ __launch_bounds__(256)
void transpose_bf16(const bf16* __restrict__ in, bf16* __restrict__ out, int R, int C) {
  __shared__ bf16 t[64][72];
  const bf16* ib = in + (size_t)blockIdx.z * R * C;
  bf16* ob = out + (size_t)blockIdx.z * R * C;
  const int r0 = blockIdx.y * 64, c0 = blockIdx.x * 64;
  const int tid = threadIdx.x;
#pragma unroll
  for (int p = 0; p < 2; p++) {
    int r = p * 32 + tid / 8, cc = (tid % 8) * 8;
    bf16x8 vv = *(const bf16x8*)(ib + (size_t)(r0 + r) * C + c0 + cc);
#pragma unroll
    for (int j = 0; j < 8; j++) t[r][cc + j] = vv[j];
  }
  __syncthreads();
#pragma unroll
  for (int p = 0; p < 2; p++) {
    int r = p * 32 + tid / 8, cc = (tid % 8) * 8;
    bf16x8 o;
#pragma unroll
    for (int j = 0; j < 8; j++) o[j] = t[cc + j][r];
    *(bf16x8*)(ob + (size_t)(c0 + r) * R + r0 + cc) = o;
  }
}

// row softmax: S (nrows x 2048 bf16) -> P (bf16), one block (256 thr) per row
__global__ __launch_bounds__(256)
void softmax_rows(const bf16* __restrict__ S, bf16* __restrict__ P) {
  const size_t row = blockIdx.x;
  const int t = threadIdx.x, wv = t >> 6, ln = t & 63;
  bf16x8 v8 = ((const bf16x8*)(S + row * 2048))[t];
  float v[8];
#pragma unroll
  for (int j = 0; j < 8; j++) v[j] = (float)v8[j];
  float m = v[0];
#pragma unroll
  for (int j = 1; j < 8; j++) m = fmaxf(m, v[j]);
  for (int o = 32; o; o >>= 1) m = fmaxf(m, __shfl_xor(m, o));
  __shared__ float redm[4], reds[4];
  if (ln == 0) redm[wv] = m;
  __syncthreads();
  m = fmaxf(fmaxf(redm[0], redm[1]), fmaxf(redm[2], redm[3]));
  float e[8], s = 0.f;
#pragma unroll
  for (int j = 0; j < 8; j++) { e[j] = __expf(v[j] - m); s += e[j]; }
  for (int o = 32; o; o >>= 1) s += __shfl_xor(s, o);
  if (ln == 0) reds[wv] = s;
  __syncthreads();
  s = reds[0] + reds[1] + reds[2] + reds[3];
  const float inv = 1.f / s;
  bf16x8 o8;
#pragma unroll
  for (int j = 0; j < 8; j++) o8[j] = (bf16)(e[j] * inv);
  ((bf16x8*)(P + row * 2048))[t] = o8;
}

extern "C" void kernel_launch(void* const* d_in, const int* in_sizes, int n_in,
                              void* d_out, int out_size, void* d_ws, size_t ws_size,
                              hipStream_t stream) {
  const float* x  = (const float*)d_in[0];
  const float* w1 = (const float*)d_in[1];
  const float* b1 = (const float*)d_in[2];
  const float* w2 = (const float*)d_in[3];
  const float* b2 = (const float*)d_in[4];
  const float* wq = (const float*)d_in[5];
  const float* bq = (const float*)d_in[6];
  const float* wk = (const float*)d_in[7];
  const float* bk = (const float*)d_in[8];
  const float* wv = (const float*)d_in[9];
  const float* bv = (const float*)d_in[10];
  const float* wo = (const float*)d_in[11];
  const float* bo = (const float*)d_in[12];
  float* out = (float*)d_out;

  char* ws = (char*)d_ws;
  const size_t MB = 1024ull * 1024ull;
  if (ws_size < 144 * MB) return;

  // weights / biases
  bf16* w1b  = (bf16*)(ws + 0 * MB);    // 4 MB
  bf16* w2b  = (bf16*)(ws + 4 * MB);    // 4 MB
  bf16* wqkb = (bf16*)(ws + 8 * MB);    // 4 MB: [2048][1024] = wq/32 ; wk
  bf16* wvb  = (bf16*)(ws + 12 * MB);   // 2 MB
  bf16* wob  = (bf16*)(ws + 14 * MB);   // 2 MB
  float* bqk = (float*)(ws + 16 * MB);  // 8 KB
  // activations (lifetime-aliased)
  bf16* xb  = (bf16*)(ws + 17 * MB);    // 16 MB, dead after G1
  bf16* h1  = (bf16*)(ws + 33 * MB);    // 32 MB, dead after G2
  bf16* h   = (bf16*)(ws + 65 * MB);    // 16 MB, dead after Gqk/Gv
  bf16* qk  = (bf16*)(ws + 81 * MB);    // 32 MB [8192][2048], dead after Gs
  bf16* vb  = (bf16*)(ws + 113 * MB);   // 16 MB, alive through Gpv (residual)
  bf16* vT  = (bf16*)(ws + 17 * MB);    // 16 MB over dead xb
  bf16* S   = (bf16*)(ws + 33 * MB);    // 32 MB over dead h1, dead after softmax
  bf16* P   = (bf16*)(ws + 65 * MB);    // 32 MB over dead h + dead qk head
  bf16* ctx = (bf16*)(ws + 33 * MB);    // 16 MB over dead S

  // ---- casts (wq cast folds the 1/sqrt(1024) attention scale) ----
  cast_f32_to_bf16<<<4096, 256, 0, stream>>>(x,  xb,  8192 * 1024 / 8, 1.f);
  cast_f32_to_bf16<<<1024, 256, 0, stream>>>(w1, w1b, 2048 * 1024 / 8, 1.f);
  cast_f32_to_bf16<<<1024, 256, 0, stream>>>(w2, w2b, 1024 * 2048 / 8, 1.f);
  cast_f32_to_bf16<<<512, 256, 0, stream>>>(wq, wqkb,                 1024 * 1024 / 8, 0.03125f);
  cast_f32_to_bf16<<<512, 256, 0, stream>>>(wk, wqkb + 1024 * 1024,   1024 * 1024 / 8, 1.f);
  cast_f32_to_bf16<<<512, 256, 0, stream>>>(wv, wvb, 1024 * 1024 / 8, 1.f);
  cast_f32_to_bf16<<<512, 256, 0, stream>>>(wo, wob, 1024 * 1024 / 8, 1.f);
  pack_bias_qk<<<8, 256, 0, stream>>>(bq, bk, bqk);

  // ---- 1: h1 = relu(x @ w1^T + b1)   M=8192 N=2048 K=1024  [256x256] 256wg
  gemm8p<EPI_BIAS_RELU, 256><<<dim3(8, 32, 1), 512, 0, stream>>>(
      xb, w1b, h1, b1, nullptr, 1024, 1024, 1024, 2048, 0, 0, 0, 0);
  // ---- 2: h = relu(h1 @ w2^T + b2)   M=8192 N=1024 K=2048  [128x256] 256wg
  gemm8p<EPI_BIAS_RELU, 128><<<dim3(4, 64, 1), 512, 0, stream>>>(
      h1, w2b, h, b2, nullptr, 2048, 2048, 2048, 1024, 0, 0, 0, 0);
  // ---- 3: [q/32 | k] = h @ wqkb^T + bqk   M=8192 N=2048 K=1024  [256x256]
  gemm8p<EPI_BIAS_BF16, 256><<<dim3(8, 32, 1), 512, 0, stream>>>(
      h, wqkb, qk, bqk, nullptr, 1024, 1024, 1024, 2048, 0, 0, 0, 0);
  // ---- 4: v = h @ wv^T + bv   M=8192 N=1024 K=1024  [128x256]
  gemm8p<EPI_BIAS_BF16, 128><<<dim3(4, 64, 1), 512, 0, stream>>>(
      h, wvb, vb, bv, nullptr, 1024, 1024, 1024, 1024, 0, 0, 0, 0);
  // ---- v^T per batch (2048x1024 -> 1024x2048)
  transpose_bf16<<<dim3(16, 32, 4), 256, 0, stream>>>(vb, vT, 2048, 1024);
  // ---- 5: S = qhat @ k^T (scale pre-folded), batched z=4  [256x256] 256wg
  gemm8p<EPI_PLAIN_BF16, 256><<<dim3(8, 8, 4), 512, 0, stream>>>(
      qk, qk + 1024, S, nullptr, nullptr, 1024, 2048, 2048, 2048,
      2048LL * 2048, 2048LL * 2048, 2048LL * 2048, 0);
  // ---- 6: P = softmax_rows(S)
  softmax_rows<<<8192, 256, 0, stream>>>(S, P);
  // ---- 7: ctx = P @ vT^T + v, batched   M=2048 N=1024 K=2048  [128x256]
  gemm8p<EPI_RESID, 128><<<dim3(4, 16, 4), 512, 0, stream>>>(
      P, vT, ctx, nullptr, vb, 2048, 2048, 2048, 1024,
      2048LL * 2048, 1024LL * 2048, 2048LL * 1024, 2048LL * 1024);
  // ---- 8: out = ctx @ wo^T + bo (fp32)   M=8192 N=1024 K=1024  [128x256]
  gemm8p<EPI_BIAS_F32, 128><<<dim3(4, 64, 1), 512, 0, stream>>>(
      ctx, wob, out, bo, nullptr, 1024, 1024, 1024, 1024, 0, 0, 0, 0);
}

// Round 6
// 275.210 us; speedup vs baseline: 1.4934x; 1.0399x over previous
//
#include <hip/hip_runtime.h>
#include <hip/hip_bf16.h>

typedef __bf16 bf16;
typedef bf16 bf16x8 __attribute__((ext_vector_type(8)));
typedef float f32x4 __attribute__((ext_vector_type(4)));

#define EPI_BIAS_RELU  0
#define EPI_BIAS_BF16  1
#define EPI_PLAIN_BF16 2
#define EPI_RESID      3
#define EPI_BIAS_F32   4

__device__ __forceinline__ void lds_load16(const bf16* g, bf16* l) {
  __builtin_amdgcn_global_load_lds((__attribute__((address_space(1))) void*)g,
                                   (__attribute__((address_space(3))) void*)l,
                                   16, 0, 0);
}

template<int N> __device__ __forceinline__ void vmw() {
  if constexpr (N == 0) asm volatile("s_waitcnt vmcnt(0)" ::: "memory");
  else if constexpr (N == 2) asm volatile("s_waitcnt vmcnt(2)" ::: "memory");
  else if constexpr (N == 4) asm volatile("s_waitcnt vmcnt(4)" ::: "memory");
  else if constexpr (N == 6) asm volatile("s_waitcnt vmcnt(6)" ::: "memory");
}
__device__ __forceinline__ void barrier() { asm volatile("s_barrier" ::: "memory"); }

// ============ 256x256 tile, 4-phase (r5 structure, unchanged) ============
template<int EPI>
__global__ __launch_bounds__(512, 2)
void gemm4p(const bf16* __restrict__ A, const bf16* __restrict__ B,
            void* __restrict__ Cv, const float* __restrict__ bias,
            const bf16* __restrict__ resid,
            int K, int lda, int ldb, int ldc, int ldr,
            long long sAz, long long sBz, long long sCz, long long sRz)
{
  constexpr int BM = 256, BK = 64;
  constexpr int M_REP = 8, N_REP = 4, MH = 4, NH = 2;
  constexpr int LA = 2, LB = 2, N3 = LA + LB + LA;

  __shared__ __align__(16) bf16 lA[2][BM * BK];
  __shared__ __align__(16) bf16 lB[2][256 * BK];

  const int gx = gridDim.x, gy = gridDim.y;
  const int nwg = gx * gy * gridDim.z;
  int o = (blockIdx.z * gy + blockIdx.y) * gx + blockIdx.x;
  o = (o & 7) * (nwg >> 3) + (o >> 3);
  const int bx = o % gx, rem = o / gx, by = rem % gy, z = rem / gy;

  const bf16* Ab = A + (size_t)z * sAz;
  const bf16* Bb = B + (size_t)z * sBz;
  const int row0 = by * BM, col0 = bx * 256;
  const int tid = threadIdx.x, w = tid >> 6, l = tid & 63;
  const int wr = w >> 2, wc = w & 3;

  const int srow = l >> 3, scb = (l & 7) ^ srow;
  const bf16* gA = Ab + (size_t)(row0 + w * 8 + srow) * lda + scb * 8;
  const bf16* gB = Bb + (size_t)(col0 + w * 8 + srow) * ldb + scb * 8;

  auto issueA = [&](int buf, int k0, int h) {
#pragma unroll
    for (int i = 0; i < LA; i++)
      lds_load16(gA + (size_t)(h * 128 + i * 64) * lda + k0,
                 &lA[buf][(h * 128 + i * 64 + w * 8) * BK]);
  };
  auto issueB = [&](int buf, int k0, int h) {
#pragma unroll
    for (int i = 0; i < LB; i++)
      lds_load16(gB + (size_t)(h * 128 + i * 64) * ldb + k0,
                 &lB[buf][(h * 128 + i * 64 + w * 8) * BK]);
  };

  const int fr = l & 15, fq = l >> 4, sw = fr & 7;
  bf16x8 aA0[MH][2], aA1[MH][2], bB0[NH][2], bB1[NH][2];
  f32x4 acc[M_REP][N_REP] = {};

  auto readA = [&](bf16x8 (&dst)[MH][2], int buf, int h) {
#pragma unroll
    for (int mm = 0; mm < MH; mm++) {
      const bf16* base = &lA[buf][(h * 128 + wr * 64 + mm * 16 + fr) * BK];
#pragma unroll
      for (int kk = 0; kk < 2; kk++)
        dst[mm][kk] = *(const bf16x8*)(base + ((kk * 4 + fq) ^ sw) * 8);
    }
  };
  auto readB = [&](bf16x8 (&dst)[NH][2], int buf, int h) {
#pragma unroll
    for (int nn = 0; nn < NH; nn++) {
      const bf16* base = &lB[buf][(h * 128 + wc * 32 + nn * 16 + fr) * BK];
#pragma unroll
      for (int kk = 0; kk < 2; kk++)
        dst[nn][kk] = *(const bf16x8*)(base + ((kk * 4 + fq) ^ sw) * 8);
    }
  };
  auto quad = [&](const bf16x8 (&a)[MH][2], const bf16x8 (&b)[NH][2],
                  int mBase, int nBase) {
    __builtin_amdgcn_s_setprio(1);
#pragma unroll
    for (int mh = 0; mh < MH; mh++)
#pragma unroll
      for (int nh = 0; nh < NH; nh++)
#pragma unroll
        for (int kk = 0; kk < 2; kk++)
          acc[mBase + mh][nBase + nh] = __builtin_amdgcn_mfma_f32_16x16x32_bf16(
              a[mh][kk], b[nh][kk], acc[mBase + mh][nBase + nh], 0, 0, 0);
    __builtin_amdgcn_s_setprio(0);
  };

  const int NT = K / BK;
  issueA(0, 0, 0); issueB(0, 0, 0); issueA(0, 0, 1); issueB(0, 0, 1);
  issueA(1, BK, 0); issueB(1, BK, 0); issueA(1, BK, 1);
  vmw<N3>();
  barrier();

  for (int t = 0; t < NT; t++) {
    const int cur = t & 1, nxt = cur ^ 1;
    const bool s1 = (t + 1 < NT), s2 = (t + 2 < NT);
    const int k1 = (t + 1) * BK, k2 = (t + 2) * BK;
    readA(aA0, cur, 0);
    readB(bB0, cur, 0);
    if (s1) issueB(nxt, k1, 1);
    barrier();
    quad(aA0, bB0, 0, 0);
    barrier();
    readA(aA1, cur, 1);
    if (s2) issueA(cur, k2, 0);
    barrier();
    quad(aA1, bB0, MH, 0);
    barrier();
    readB(bB1, cur, 1);
    if (s2) issueB(cur, k2, 0);
    barrier();
    quad(aA1, bB1, MH, NH);
    barrier();
    if (s2) { issueA(cur, k2, 1); vmw<N3>(); }
    else vmw<0>();
    barrier();
    quad(aA0, bB1, 0, NH);
    barrier();
  }

#pragma unroll
  for (int m = 0; m < M_REP; m++) {
#pragma unroll
    for (int n = 0; n < N_REP; n++) {
      const int col = col0 + (n / NH) * 128 + wc * 32 + (n % NH) * 16 + fr;
#pragma unroll
      for (int j = 0; j < 4; j++) {
        const int rrow = row0 + (m / MH) * 128 + wr * 64 + (m % MH) * 16 + fq * 4 + j;
        const float val = acc[m][n][j];
        if constexpr (EPI == EPI_PLAIN_BF16) {
          bf16* Cp = (bf16*)Cv + (size_t)z * sCz;
          Cp[(size_t)rrow * ldc + col] = (bf16)val;
        } else if constexpr (EPI == EPI_BIAS_F32) {
          float* Cp = (float*)Cv;
          Cp[(size_t)rrow * ldc + col] = val + bias[col];
        } else if constexpr (EPI == EPI_BIAS_BF16) {
          bf16* Cp = (bf16*)Cv;
          Cp[(size_t)rrow * ldc + col] = (bf16)(val + bias[col]);
        } else if constexpr (EPI == EPI_BIAS_RELU) {
          bf16* Cp = (bf16*)Cv;
          Cp[(size_t)rrow * ldc + col] = (bf16)fmaxf(val + bias[col], 0.f);
        } else {
          bf16* Cp = (bf16*)Cv + (size_t)z * sCz;
          const bf16* Rp = resid + (size_t)z * sRz;
          Cp[(size_t)rrow * ldc + col] = (bf16)(val + (float)Rp[(size_t)rrow * ldr + col]);
        }
      }
    }
  }
}

// ============ 128x256 tile, 2-phase/K-tile: 16-MFMA phases ============
// Waves 2M x 4N: WM=64 (wr*64), per-wave cols = {h*128 + wc*32 .. +31} per half.
// Phase p0: readA(full,t)+readB(B0,t) | stage B(t+1)->lB[nxt] | bar | 16 MFMA | bar
// Phase p1: readB(B1,t)              | stage A(t+2)->lA[cur] + vmcnt(2) | bar | 16 MFMA | bar
// Ledger: B(t+1) overwrites lB[nxt] whose last read (B1,t-1) drained before
// p1(t-1)'s closing barrier. A(t+2) overwrites lA[cur] whose last read (p0(t))
// drained before p0's closing barrier. vmcnt(2) at p1(t) leaves only A(t+2)
// outstanding -> forces B(t+1) [issued p0(t)] and A(t+1) [issued p1(t-1)].
template<int EPI>
__global__ __launch_bounds__(512, 2)
void gemm2p(const bf16* __restrict__ A, const bf16* __restrict__ B,
            void* __restrict__ Cv, const float* __restrict__ bias,
            const bf16* __restrict__ resid,
            int K, int lda, int ldb, int ldc, int ldr,
            long long sAz, long long sBz, long long sCz, long long sRz)
{
  constexpr int BM = 128, BK = 64;
  constexpr int M_REP = 4, NH = 2;

  __shared__ __align__(16) bf16 lA[2][BM * BK];
  __shared__ __align__(16) bf16 lB[2][256 * BK];

  const int gx = gridDim.x, gy = gridDim.y;
  const int nwg = gx * gy * gridDim.z;
  int o = (blockIdx.z * gy + blockIdx.y) * gx + blockIdx.x;
  o = (o & 7) * (nwg >> 3) + (o >> 3);
  const int bx = o % gx, rem = o / gx, by = rem % gy, z = rem / gy;

  const bf16* Ab = A + (size_t)z * sAz;
  const bf16* Bb = B + (size_t)z * sBz;
  const int row0 = by * BM, col0 = bx * 256;
  const int tid = threadIdx.x, w = tid >> 6, l = tid & 63;
  const int wr = w >> 2, wc = w & 3;

  const int srow = l >> 3, scb = (l & 7) ^ srow;
  const bf16* gA = Ab + (size_t)(row0 + w * 8 + srow) * lda + scb * 8;
  const bf16* gB = Bb + (size_t)(col0 + w * 8 + srow) * ldb + scb * 8;

  auto issueAfull = [&](int buf, int k0) {  // 2 loads/wave (128x64 tile)
#pragma unroll
    for (int i = 0; i < 2; i++)
      lds_load16(gA + (size_t)(i * 64) * lda + k0,
                 &lA[buf][(i * 64 + w * 8) * BK]);
  };
  auto issueBfull = [&](int buf, int k0) {  // 4 loads/wave (256x64 tile)
#pragma unroll
    for (int i = 0; i < 4; i++)
      lds_load16(gB + (size_t)(i * 64) * ldb + k0,
                 &lB[buf][(i * 64 + w * 8) * BK]);
  };

  const int fr = l & 15, fq = l >> 4, sw = fr & 7;
  bf16x8 aA[M_REP][2], bB0[NH][2], bB1[NH][2];
  f32x4 acc[M_REP][4] = {};

  auto readAfull = [&](int buf) {
#pragma unroll
    for (int m = 0; m < M_REP; m++) {
      const bf16* base = &lA[buf][(wr * 64 + m * 16 + fr) * BK];
#pragma unroll
      for (int kk = 0; kk < 2; kk++)
        aA[m][kk] = *(const bf16x8*)(base + ((kk * 4 + fq) ^ sw) * 8);
    }
  };
  auto readB = [&](bf16x8 (&dst)[NH][2], int buf, int h) {
#pragma unroll
    for (int nn = 0; nn < NH; nn++) {
      const bf16* base = &lB[buf][(h * 128 + wc * 32 + nn * 16 + fr) * BK];
#pragma unroll
      for (int kk = 0; kk < 2; kk++)
        dst[nn][kk] = *(const bf16x8*)(base + ((kk * 4 + fq) ^ sw) * 8);
    }
  };
  auto quad2 = [&](const bf16x8 (&b)[NH][2], int nBase) {
    __builtin_amdgcn_s_setprio(1);
#pragma unroll
    for (int m = 0; m < M_REP; m++)
#pragma unroll
      for (int nh = 0; nh < NH; nh++)
#pragma unroll
        for (int kk = 0; kk < 2; kk++)
          acc[m][nBase + nh] = __builtin_amdgcn_mfma_f32_16x16x32_bf16(
              aA[m][kk], b[nh][kk], acc[m][nBase + nh], 0, 0, 0);
    __builtin_amdgcn_s_setprio(0);
  };

  const int NT = K / BK;
  // prologue FIFO: A(0):2, B(0):4, A(1):2 -> vmcnt(2) forces tile0
  issueAfull(0, 0); issueBfull(0, 0); issueAfull(1, BK);
  vmw<2>();
  barrier();

  for (int t = 0; t < NT; t++) {
    const int cur = t & 1, nxt = cur ^ 1;
    const bool s1 = (t + 1 < NT), s2 = (t + 2 < NT);
    // p0
    readAfull(cur);
    readB(bB0, cur, 0);
    if (s1) issueBfull(nxt, (t + 1) * BK);
    barrier();
    quad2(bB0, 0);
    barrier();
    // p1
    readB(bB1, cur, 1);
    if (s2) { issueAfull(cur, (t + 2) * BK); vmw<2>(); }
    else vmw<0>();
    barrier();
    quad2(bB1, NH);
    barrier();
  }

#pragma unroll
  for (int m = 0; m < M_REP; m++) {
#pragma unroll
    for (int n = 0; n < 4; n++) {
      const int col = col0 + (n / NH) * 128 + wc * 32 + (n % NH) * 16 + fr;
#pragma unroll
      for (int j = 0; j < 4; j++) {
        const int rrow = row0 + wr * 64 + m * 16 + fq * 4 + j;
        const float val = acc[m][n][j];
        if constexpr (EPI == EPI_PLAIN_BF16) {
          bf16* Cp = (bf16*)Cv + (size_t)z * sCz;
          Cp[(size_t)rrow * ldc + col] = (bf16)val;
        } else if constexpr (EPI == EPI_BIAS_F32) {
          float* Cp = (float*)Cv;
          Cp[(size_t)rrow * ldc + col] = val + bias[col];
        } else if constexpr (EPI == EPI_BIAS_BF16) {
          bf16* Cp = (bf16*)Cv;
          Cp[(size_t)rrow * ldc + col] = (bf16)(val + bias[col]);
        } else if constexpr (EPI == EPI_BIAS_RELU) {
          bf16* Cp = (bf16*)Cv;
          Cp[(size_t)rrow * ldc + col] = (bf16)fmaxf(val + bias[col], 0.f);
        } else {  // EPI_RESID
          bf16* Cp = (bf16*)Cv + (size_t)z * sCz;
          const bf16* Rp = resid + (size_t)z * sRz;
          Cp[(size_t)rrow * ldc + col] = (bf16)(val + (float)Rp[(size_t)rrow * ldr + col]);
        }
      }
    }
  }
}

// ===== single cast kernel: x + all weights (block-range dispatch) =====
__global__ __launch_bounds__(256)
void cast_all(const float* __restrict__ x,  const float* __restrict__ w1,
              const float* __restrict__ w2, const float* __restrict__ wq,
              const float* __restrict__ wk, const float* __restrict__ wv,
              const float* __restrict__ wo,
              bf16* __restrict__ xb, bf16* __restrict__ w1b,
              bf16* __restrict__ w2b, bf16* __restrict__ wqkvb,
              bf16* __restrict__ wob) {
  const int b = blockIdx.x;
  const float* src; bf16* dst; int base; float scale = 1.f;
  if (b < 4096)      { src = x;  dst = xb;    base = b; }
  else if (b < 5120) { src = w1; dst = w1b;   base = b - 4096; }
  else if (b < 6144) { src = w2; dst = w2b;   base = b - 5120; }
  else if (b < 6656) { src = wq; dst = wqkvb;                base = b - 6144; scale = 0.03125f; }
  else if (b < 7168) { src = wk; dst = wqkvb + (1 << 20);    base = b - 6656; }
  else if (b < 7680) { src = wv; dst = wqkvb + (2 << 20);    base = b - 7168; }
  else               { src = wo; dst = wob;   base = b - 7680; }
  const int i = base * 256 + threadIdx.x;  // 8-elem group index
  const float4* p = (const float4*)src;
  float4 a = p[2 * i], c = p[2 * i + 1];
  bf16x8 o8;
  o8[0] = (bf16)(a.x * scale); o8[1] = (bf16)(a.y * scale);
  o8[2] = (bf16)(a.z * scale); o8[3] = (bf16)(a.w * scale);
  o8[4] = (bf16)(c.x * scale); o8[5] = (bf16)(c.y * scale);
  o8[6] = (bf16)(c.z * scale); o8[7] = (bf16)(c.w * scale);
  ((bf16x8*)dst)[i] = o8;
}

__global__ __launch_bounds__(256)
void pack_bias_qkv(const float* __restrict__ bq, const float* __restrict__ bk,
                   const float* __restrict__ bv, float* __restrict__ o) {
  int i = blockIdx.x * 256 + threadIdx.x;  // 3072
  o[i] = (i < 1024) ? bq[i] * 0.03125f : (i < 2048 ? bk[i - 1024] : bv[i - 2048]);
}

// batched transpose: in (z, R x C with ld ldi) -> out (z, C x R)
__global__ __launch_bounds__(256)
void transpose_bf16(const bf16* __restrict__ in, bf16* __restrict__ out,
                    int R, int C, int ldi,
                    long long inZ, long long outZ) {
  __shared__ bf16 t[64][72];
  const bf16* ib = in + (size_t)blockIdx.z * inZ;
  bf16* ob = out + (size_t)blockIdx.z * outZ;
  const int r0 = blockIdx.y * 64, c0 = blockIdx.x * 64;
  const int tid = threadIdx.x;
#pragma unroll
  for (int p = 0; p < 2; p++) {
    int r = p * 32 + tid / 8, cc = (tid % 8) * 8;
    bf16x8 vv = *(const bf16x8*)(ib + (size_t)(r0 + r) * ldi + c0 + cc);
#pragma unroll
    for (int j = 0; j < 8; j++) t[r][cc + j] = vv[j];
  }
  __syncthreads();
#pragma unroll
  for (int p = 0; p < 2; p++) {
    int r = p * 32 + tid / 8, cc = (tid % 8) * 8;
    bf16x8 o;
#pragma unroll
    for (int j = 0; j < 8; j++) o[j] = t[cc + j][r];
    *(bf16x8*)(ob + (size_t)(c0 + r) * R + r0 + cc) = o;
  }
}

// row softmax in-place: S (nrows x 2048 bf16)
__global__ __launch_bounds__(256)
void softmax_rows(bf16* __restrict__ S) {
  const size_t row = blockIdx.x;
  const int t = threadIdx.x, wv_ = t >> 6, ln = t & 63;
  bf16x8 v8 = ((const bf16x8*)(S + row * 2048))[t];
  float v[8];
#pragma unroll
  for (int j = 0; j < 8; j++) v[j] = (float)v8[j];
  float m = v[0];
#pragma unroll
  for (int j = 1; j < 8; j++) m = fmaxf(m, v[j]);
  for (int o = 32; o; o >>= 1) m = fmaxf(m, __shfl_xor(m, o));
  __shared__ float redm[4], reds[4];
  if (ln == 0) redm[wv_] = m;
  __syncthreads();
  m = fmaxf(fmaxf(redm[0], redm[1]), fmaxf(redm[2], redm[3]));
  float e[8], s = 0.f;
#pragma unroll
  for (int j = 0; j < 8; j++) { e[j] = __expf(v[j] - m); s += e[j]; }
  for (int o = 32; o; o >>= 1) s += __shfl_xor(s, o);
  if (ln == 0) reds[wv_] = s;
  __syncthreads();
  s = reds[0] + reds[1] + reds[2] + reds[3];
  const float inv = 1.f / s;
  bf16x8 o8;
#pragma unroll
  for (int j = 0; j < 8; j++) o8[j] = (bf16)(e[j] * inv);
  ((bf16x8*)(S + row * 2048))[t] = o8;
}

extern "C" void kernel_launch(void* const* d_in, const int* in_sizes, int n_in,
                              void* d_out, int out_size, void* d_ws, size_t ws_size,
                              hipStream_t stream) {
  const float* x  = (const float*)d_in[0];
  const float* w1 = (const float*)d_in[1];
  const float* b1 = (const float*)d_in[2];
  const float* w2 = (const float*)d_in[3];
  const float* b2 = (const float*)d_in[4];
  const float* wq = (const float*)d_in[5];
  const float* bq = (const float*)d_in[6];
  const float* wk = (const float*)d_in[7];
  const float* bk = (const float*)d_in[8];
  const float* wv = (const float*)d_in[9];
  const float* bv = (const float*)d_in[10];
  const float* wo = (const float*)d_in[11];
  const float* bo = (const float*)d_in[12];
  float* out = (float*)d_out;

  char* ws = (char*)d_ws;
  const size_t MB = 1024ull * 1024ull;
  if (ws_size < 130 * MB) return;

  bf16* w1b   = (bf16*)(ws + 0 * MB);   // 4 MB
  bf16* w2b   = (bf16*)(ws + 4 * MB);   // 4 MB
  bf16* wqkvb = (bf16*)(ws + 8 * MB);   // 6 MB: [3072][1024] = wq/32 ; wk ; wv
  bf16* wob   = (bf16*)(ws + 14 * MB);  // 2 MB
  float* bqkv = (float*)(ws + 16 * MB); // 12 KB
  bf16* xb  = (bf16*)(ws + 17 * MB);    // 16 MB, dead after G1
  bf16* h1  = (bf16*)(ws + 33 * MB);    // 32 MB, dead after G2
  bf16* h   = (bf16*)(ws + 65 * MB);    // 16 MB, dead after Gqkv
  bf16* qkv = (bf16*)(ws + 81 * MB);    // 48 MB [8192][3072], alive thru PV
  bf16* vT  = (bf16*)(ws + 17 * MB);    // 16 MB over dead xb
  bf16* S   = (bf16*)(ws + 33 * MB);    // 32 MB over dead h1 (softmax in-place)
  bf16* ctx = (bf16*)(ws + 65 * MB);    // 16 MB over dead h

  // ---- casts (wq fold 1/32 scale) + bias pack: 2 dispatches ----
  cast_all<<<8192, 256, 0, stream>>>(x, w1, w2, wq, wk, wv, wo,
                                     xb, w1b, w2b, wqkvb, wob);
  pack_bias_qkv<<<12, 256, 0, stream>>>(bq, bk, bv, bqkv);

  // ---- 1: h1 = relu(x @ w1^T + b1)   M=8192 N=2048 K=1024  [256x256 4ph]
  gemm4p<EPI_BIAS_RELU><<<dim3(8, 32, 1), 512, 0, stream>>>(
      xb, w1b, h1, b1, nullptr, 1024, 1024, 1024, 2048, 0, 0, 0, 0, 0);
  // ---- 2: h = relu(h1 @ w2^T + b2)   M=8192 N=1024 K=2048  [128x256 2ph]
  gemm2p<EPI_BIAS_RELU><<<dim3(4, 64, 1), 512, 0, stream>>>(
      h1, w2b, h, b2, nullptr, 2048, 2048, 2048, 1024, 0, 0, 0, 0, 0);
  // ---- 3: [q/32|k|v] = h @ wqkvb^T + bqkv   M=8192 N=3072 K=1024  [256x256]
  gemm4p<EPI_BIAS_BF16><<<dim3(12, 32, 1), 512, 0, stream>>>(
      h, wqkvb, qkv, bqkv, nullptr, 1024, 1024, 1024, 3072, 0, 0, 0, 0, 0);
  // ---- v^T per batch: v = qkv[:,2048:3072], (2048 x 1024, ld 3072) -> vT
  transpose_bf16<<<dim3(16, 32, 4), 256, 0, stream>>>(
      qkv + 2048, vT, 2048, 1024, 3072, 2048LL * 3072, 1024LL * 2048);
  // ---- 4: S = qhat @ k^T (scale pre-folded), batched z=4  [256x256 4ph]
  gemm4p<EPI_PLAIN_BF16><<<dim3(8, 8, 4), 512, 0, stream>>>(
      qkv, qkv + 1024, S, nullptr, nullptr, 1024, 3072, 3072, 2048, 0,
      2048LL * 3072, 2048LL * 3072, 2048LL * 2048, 0);
  // ---- 5: P = softmax(S) in-place
  softmax_rows<<<8192, 256, 0, stream>>>(S);
  // ---- 6: ctx = P @ vT^T + v, batched   M=2048 N=1024 K=2048  [128x256 2ph]
  gemm2p<EPI_RESID><<<dim3(4, 16, 4), 512, 0, stream>>>(
      S, vT, ctx, nullptr, qkv + 2048, 2048, 2048, 2048, 1024, 3072,
      2048LL * 2048, 1024LL * 2048, 2048LL * 1024, 2048LL * 3072);
  // ---- 7: out = ctx @ wo^T + bo (fp32)   M=8192 N=1024 K=1024  [128x256 2ph]
  gemm2p<EPI_BIAS_F32><<<dim3(4, 64, 1), 512, 0, stream>>>(
      ctx, wob, out, bo, nullptr, 1024, 1024, 1024, 1024, 0, 0, 0, 0, 0);
}

// Round 7
// 268.430 us; speedup vs baseline: 1.5311x; 1.0253x over previous
//
#include <hip/hip_runtime.h>
#include <hip/hip_bf16.h>

typedef __bf16 bf16;
typedef bf16 bf16x8 __attribute__((ext_vector_type(8)));
typedef float f32x4 __attribute__((ext_vector_type(4)));

#define EPI_BIAS_RELU  0
#define EPI_BIAS_BF16  1
#define EPI_PLAIN_BF16 2
#define EPI_RESID      3
#define EPI_BIAS_F32   4

__device__ __forceinline__ void lds_load16(const bf16* g, bf16* l) {
  __builtin_amdgcn_global_load_lds((__attribute__((address_space(1))) void*)g,
                                   (__attribute__((address_space(3))) void*)l,
                                   16, 0, 0);
}

template<int N> __device__ __forceinline__ void vmw() {
  if constexpr (N == 0) asm volatile("s_waitcnt vmcnt(0)" ::: "memory");
  else if constexpr (N == 2) asm volatile("s_waitcnt vmcnt(2)" ::: "memory");
  else if constexpr (N == 4) asm volatile("s_waitcnt vmcnt(4)" ::: "memory");
  else if constexpr (N == 6) asm volatile("s_waitcnt vmcnt(6)" ::: "memory");
}
__device__ __forceinline__ void barrier() { asm volatile("s_barrier" ::: "memory"); }

// Row-slab XCD mapping: XCD x owns contiguous (z,by) slab of size Y/8 so its
// 32 resident blocks share a ~2-4 MB A-slab (L2-resident); bx varies fastest.
// Bijective when nwg%8==0 and (gy*gz)%8==0 (true for all our grids).
__device__ __forceinline__ void xcd_map(int& bx, int& by, int& z) {
  const int gx = gridDim.x, gy = gridDim.y;
  const int Y8 = (gy * gridDim.z) >> 3;
  const int L = (blockIdx.z * gy + blockIdx.y) * gx + blockIdx.x;
  const int xcd = L & 7, j = L >> 3;
  bx = j % gx;
  const int yy = xcd * Y8 + j / gx;
  by = yy % gy;
  z  = yy / gy;
}

// ============ 256x256 tile, 4-phase (r5/r6-proven ledger) ============
template<int EPI>
__global__ __launch_bounds__(512, 2)
void gemm4p(const bf16* __restrict__ A, const bf16* __restrict__ B,
            void* __restrict__ Cv, const float* __restrict__ bias,
            int K, int lda, int ldb, int ldc,
            long long sAz, long long sBz, long long sCz)
{
  constexpr int BM = 256, BK = 64;
  constexpr int M_REP = 8, N_REP = 4, MH = 4, NH = 2;
  constexpr int LA = 2, LB = 2, N3 = LA + LB + LA;

  __shared__ __align__(16) bf16 lA[2][BM * BK];
  __shared__ __align__(16) bf16 lB[2][256 * BK];

  int bx, by, z;
  xcd_map(bx, by, z);

  const bf16* Ab = A + (size_t)z * sAz;
  const bf16* Bb = B + (size_t)z * sBz;
  const int row0 = by * BM, col0 = bx * 256;
  const int tid = threadIdx.x, w = tid >> 6, l = tid & 63;
  const int wr = w >> 2, wc = w & 3;

  const int srow = l >> 3, scb = (l & 7) ^ srow;
  const bf16* gA = Ab + (size_t)(row0 + w * 8 + srow) * lda + scb * 8;
  const bf16* gB = Bb + (size_t)(col0 + w * 8 + srow) * ldb + scb * 8;

  auto issueA = [&](int buf, int k0, int h) {
#pragma unroll
    for (int i = 0; i < LA; i++)
      lds_load16(gA + (size_t)(h * 128 + i * 64) * lda + k0,
                 &lA[buf][(h * 128 + i * 64 + w * 8) * BK]);
  };
  auto issueB = [&](int buf, int k0, int h) {
#pragma unroll
    for (int i = 0; i < LB; i++)
      lds_load16(gB + (size_t)(h * 128 + i * 64) * ldb + k0,
                 &lB[buf][(h * 128 + i * 64 + w * 8) * BK]);
  };

  const int fr = l & 15, fq = l >> 4, sw = fr & 7;
  bf16x8 aA0[MH][2], aA1[MH][2], bB0[NH][2], bB1[NH][2];
  f32x4 acc[M_REP][N_REP] = {};

  auto readA = [&](bf16x8 (&dst)[MH][2], int buf, int h) {
#pragma unroll
    for (int mm = 0; mm < MH; mm++) {
      const bf16* base = &lA[buf][(h * 128 + wr * 64 + mm * 16 + fr) * BK];
#pragma unroll
      for (int kk = 0; kk < 2; kk++)
        dst[mm][kk] = *(const bf16x8*)(base + ((kk * 4 + fq) ^ sw) * 8);
    }
  };
  auto readB = [&](bf16x8 (&dst)[NH][2], int buf, int h) {
#pragma unroll
    for (int nn = 0; nn < NH; nn++) {
      const bf16* base = &lB[buf][(h * 128 + wc * 32 + nn * 16 + fr) * BK];
#pragma unroll
      for (int kk = 0; kk < 2; kk++)
        dst[nn][kk] = *(const bf16x8*)(base + ((kk * 4 + fq) ^ sw) * 8);
    }
  };
  auto quad = [&](const bf16x8 (&a)[MH][2], const bf16x8 (&b)[NH][2],
                  int mBase, int nBase) {
    __builtin_amdgcn_s_setprio(1);
#pragma unroll
    for (int mh = 0; mh < MH; mh++)
#pragma unroll
      for (int nh = 0; nh < NH; nh++)
#pragma unroll
        for (int kk = 0; kk < 2; kk++)
          acc[mBase + mh][nBase + nh] = __builtin_amdgcn_mfma_f32_16x16x32_bf16(
              a[mh][kk], b[nh][kk], acc[mBase + mh][nBase + nh], 0, 0, 0);
    __builtin_amdgcn_s_setprio(0);
  };

  const int NT = K / BK;
  issueA(0, 0, 0); issueB(0, 0, 0); issueA(0, 0, 1); issueB(0, 0, 1);
  issueA(1, BK, 0); issueB(1, BK, 0); issueA(1, BK, 1);
  vmw<N3>();
  barrier();

  for (int t = 0; t < NT; t++) {
    const int cur = t & 1, nxt = cur ^ 1;
    const bool s1 = (t + 1 < NT), s2 = (t + 2 < NT);
    const int k1 = (t + 1) * BK, k2 = (t + 2) * BK;
    readA(aA0, cur, 0);
    readB(bB0, cur, 0);
    if (s1) issueB(nxt, k1, 1);
    barrier();
    quad(aA0, bB0, 0, 0);
    barrier();
    readA(aA1, cur, 1);
    if (s2) issueA(cur, k2, 0);
    barrier();
    quad(aA1, bB0, MH, 0);
    barrier();
    readB(bB1, cur, 1);
    if (s2) issueB(cur, k2, 0);
    barrier();
    quad(aA1, bB1, MH, NH);
    barrier();
    if (s2) { issueA(cur, k2, 1); vmw<N3>(); }
    else vmw<0>();
    barrier();
    quad(aA0, bB1, 0, NH);
    barrier();
  }

#pragma unroll
  for (int m = 0; m < M_REP; m++) {
#pragma unroll
    for (int n = 0; n < N_REP; n++) {
      const int col = col0 + (n / NH) * 128 + wc * 32 + (n % NH) * 16 + fr;
#pragma unroll
      for (int j = 0; j < 4; j++) {
        const int rrow = row0 + (m / MH) * 128 + wr * 64 + (m % MH) * 16 + fq * 4 + j;
        const float val = acc[m][n][j];
        if constexpr (EPI == EPI_PLAIN_BF16) {
          bf16* Cp = (bf16*)Cv + (size_t)z * sCz;
          Cp[(size_t)rrow * ldc + col] = (bf16)val;
        } else if constexpr (EPI == EPI_BIAS_BF16) {
          bf16* Cp = (bf16*)Cv;
          Cp[(size_t)rrow * ldc + col] = (bf16)(val + bias[col]);
        } else if constexpr (EPI == EPI_BIAS_RELU) {
          bf16* Cp = (bf16*)Cv;
          Cp[(size_t)rrow * ldc + col] = (bf16)fmaxf(val + bias[col], 0.f);
        }
      }
    }
  }
}

// ============ 128x256 tile, 2-phase (r6-proven ledger) ============
template<int EPI>
__global__ __launch_bounds__(512, 2)
void gemm2p(const bf16* __restrict__ A, const bf16* __restrict__ B,
            void* __restrict__ Cv, const float* __restrict__ bias,
            const bf16* __restrict__ resid,
            int K, int lda, int ldb, int ldc, int ldr,
            long long sAz, long long sBz, long long sCz, long long sRz)
{
  constexpr int BM = 128, BK = 64;
  constexpr int M_REP = 4, NH = 2;

  __shared__ __align__(16) bf16 lA[2][BM * BK];
  __shared__ __align__(16) bf16 lB[2][256 * BK];

  int bx, by, z;
  xcd_map(bx, by, z);

  const bf16* Ab = A + (size_t)z * sAz;
  const bf16* Bb = B + (size_t)z * sBz;
  const int row0 = by * BM, col0 = bx * 256;
  const int tid = threadIdx.x, w = tid >> 6, l = tid & 63;
  const int wr = w >> 2, wc = w & 3;

  const int srow = l >> 3, scb = (l & 7) ^ srow;
  const bf16* gA = Ab + (size_t)(row0 + w * 8 + srow) * lda + scb * 8;
  const bf16* gB = Bb + (size_t)(col0 + w * 8 + srow) * ldb + scb * 8;

  auto issueAfull = [&](int buf, int k0) {
#pragma unroll
    for (int i = 0; i < 2; i++)
      lds_load16(gA + (size_t)(i * 64) * lda + k0,
                 &lA[buf][(i * 64 + w * 8) * BK]);
  };
  auto issueBfull = [&](int buf, int k0) {
#pragma unroll
    for (int i = 0; i < 4; i++)
      lds_load16(gB + (size_t)(i * 64) * ldb + k0,
                 &lB[buf][(i * 64 + w * 8) * BK]);
  };

  const int fr = l & 15, fq = l >> 4, sw = fr & 7;
  bf16x8 aA[M_REP][2], bB0[NH][2], bB1[NH][2];
  f32x4 acc[M_REP][4] = {};

  auto readAfull = [&](int buf) {
#pragma unroll
    for (int m = 0; m < M_REP; m++) {
      const bf16* base = &lA[buf][(wr * 64 + m * 16 + fr) * BK];
#pragma unroll
      for (int kk = 0; kk < 2; kk++)
        aA[m][kk] = *(const bf16x8*)(base + ((kk * 4 + fq) ^ sw) * 8);
    }
  };
  auto readB = [&](bf16x8 (&dst)[NH][2], int buf, int h) {
#pragma unroll
    for (int nn = 0; nn < NH; nn++) {
      const bf16* base = &lB[buf][(h * 128 + wc * 32 + nn * 16 + fr) * BK];
#pragma unroll
      for (int kk = 0; kk < 2; kk++)
        dst[nn][kk] = *(const bf16x8*)(base + ((kk * 4 + fq) ^ sw) * 8);
    }
  };
  auto quad2 = [&](const bf16x8 (&b)[NH][2], int nBase) {
    __builtin_amdgcn_s_setprio(1);
#pragma unroll
    for (int m = 0; m < M_REP; m++)
#pragma unroll
      for (int nh = 0; nh < NH; nh++)
#pragma unroll
        for (int kk = 0; kk < 2; kk++)
          acc[m][nBase + nh] = __builtin_amdgcn_mfma_f32_16x16x32_bf16(
              aA[m][kk], b[nh][kk], acc[m][nBase + nh], 0, 0, 0);
    __builtin_amdgcn_s_setprio(0);
  };

  const int NT = K / BK;
  issueAfull(0, 0); issueBfull(0, 0); issueAfull(1, BK);
  vmw<2>();
  barrier();

  for (int t = 0; t < NT; t++) {
    const int cur = t & 1, nxt = cur ^ 1;
    const bool s1 = (t + 1 < NT), s2 = (t + 2 < NT);
    readAfull(cur);
    readB(bB0, cur, 0);
    if (s1) issueBfull(nxt, (t + 1) * BK);
    barrier();
    quad2(bB0, 0);
    barrier();
    readB(bB1, cur, 1);
    if (s2) { issueAfull(cur, (t + 2) * BK); vmw<2>(); }
    else vmw<0>();
    barrier();
    quad2(bB1, NH);
    barrier();
  }

#pragma unroll
  for (int m = 0; m < M_REP; m++) {
#pragma unroll
    for (int n = 0; n < 4; n++) {
      const int col = col0 + (n / NH) * 128 + wc * 32 + (n % NH) * 16 + fr;
#pragma unroll
      for (int j = 0; j < 4; j++) {
        const int rrow = row0 + wr * 64 + m * 16 + fq * 4 + j;
        const float val = acc[m][n][j];
        if constexpr (EPI == EPI_PLAIN_BF16) {
          bf16* Cp = (bf16*)Cv + (size_t)z * sCz;
          Cp[(size_t)rrow * ldc + col] = (bf16)val;
        } else if constexpr (EPI == EPI_BIAS_F32) {
          float* Cp = (float*)Cv;
          Cp[(size_t)rrow * ldc + col] = val + bias[col];
        } else if constexpr (EPI == EPI_BIAS_BF16) {
          bf16* Cp = (bf16*)Cv;
          Cp[(size_t)rrow * ldc + col] = (bf16)(val + bias[col]);
        } else if constexpr (EPI == EPI_BIAS_RELU) {
          bf16* Cp = (bf16*)Cv;
          Cp[(size_t)rrow * ldc + col] = (bf16)fmaxf(val + bias[col], 0.f);
        } else {  // EPI_RESID
          bf16* Cp = (bf16*)Cv + (size_t)z * sCz;
          const bf16* Rp = resid + (size_t)z * sRz;
          Cp[(size_t)rrow * ldc + col] = (bf16)(val + (float)Rp[(size_t)rrow * ldr + col]);
        }
      }
    }
  }
}

// ===== single cast kernel: x + all weights (block-range dispatch) =====
__global__ __launch_bounds__(256)
void cast_all(const float* __restrict__ x,  const float* __restrict__ w1,
              const float* __restrict__ w2, const float* __restrict__ wq,
              const float* __restrict__ wk, const float* __restrict__ wv,
              const float* __restrict__ wo,
              bf16* __restrict__ xb, bf16* __restrict__ w1b,
              bf16* __restrict__ w2b, bf16* __restrict__ wqkb,
              bf16* __restrict__ wvb, bf16* __restrict__ wob) {
  const int b = blockIdx.x;
  const float* src; bf16* dst; int base; float scale = 1.f;
  if (b < 4096)      { src = x;  dst = xb;   base = b; }
  else if (b < 5120) { src = w1; dst = w1b;  base = b - 4096; }
  else if (b < 6144) { src = w2; dst = w2b;  base = b - 5120; }
  else if (b < 6656) { src = wq; dst = wqkb;              base = b - 6144; scale = 0.03125f; }
  else if (b < 7168) { src = wk; dst = wqkb + (1 << 20);  base = b - 6656; }
  else if (b < 7680) { src = wv; dst = wvb;  base = b - 7168; }
  else               { src = wo; dst = wob;  base = b - 7680; }
  const int i = base * 256 + threadIdx.x;
  const float4* p = (const float4*)src;
  float4 a = p[2 * i], c = p[2 * i + 1];
  bf16x8 o8;
  o8[0] = (bf16)(a.x * scale); o8[1] = (bf16)(a.y * scale);
  o8[2] = (bf16)(a.z * scale); o8[3] = (bf16)(a.w * scale);
  o8[4] = (bf16)(c.x * scale); o8[5] = (bf16)(c.y * scale);
  o8[6] = (bf16)(c.z * scale); o8[7] = (bf16)(c.w * scale);
  ((bf16x8*)dst)[i] = o8;
}

__global__ __launch_bounds__(256)
void pack_bias_qk(const float* __restrict__ bq, const float* __restrict__ bk,
                  float* __restrict__ o) {
  int i = blockIdx.x * 256 + threadIdx.x;  // 2048
  o[i] = (i < 1024) ? bq[i] * 0.03125f : bk[i - 1024];
}

// batched transpose: in (z, R x C, ld ldi) -> out (z, C x R)
__global__ __launch_bounds__(256)
void transpose_bf16(const bf16* __restrict__ in, bf16* __restrict__ out,
                    int R, int C, int ldi,
                    long long inZ, long long outZ) {
  __shared__ bf16 t[64][72];
  const bf16* ib = in + (size_t)blockIdx.z * inZ;
  bf16* ob = out + (size_t)blockIdx.z * outZ;
  const int r0 = blockIdx.y * 64, c0 = blockIdx.x * 64;
  const int tid = threadIdx.x;
#pragma unroll
  for (int p = 0; p < 2; p++) {
    int r = p * 32 + tid / 8, cc = (tid % 8) * 8;
    bf16x8 vv = *(const bf16x8*)(ib + (size_t)(r0 + r) * ldi + c0 + cc);
#pragma unroll
    for (int j = 0; j < 8; j++) t[r][cc + j] = vv[j];
  }
  __syncthreads();
#pragma unroll
  for (int p = 0; p < 2; p++) {
    int r = p * 32 + tid / 8, cc = (tid % 8) * 8;
    bf16x8 o;
#pragma unroll
    for (int j = 0; j < 8; j++) o[j] = t[cc + j][r];
    *(bf16x8*)(ob + (size_t)(c0 + r) * R + r0 + cc) = o;
  }
}

// row softmax in-place: S (nrows x 2048 bf16)
__global__ __launch_bounds__(256)
void softmax_rows(bf16* __restrict__ S) {
  const size_t row = blockIdx.x;
  const int t = threadIdx.x, wv_ = t >> 6, ln = t & 63;
  bf16x8 v8 = ((const bf16x8*)(S + row * 2048))[t];
  float v[8];
#pragma unroll
  for (int j = 0; j < 8; j++) v[j] = (float)v8[j];
  float m = v[0];
#pragma unroll
  for (int j = 1; j < 8; j++) m = fmaxf(m, v[j]);
  for (int o = 32; o; o >>= 1) m = fmaxf(m, __shfl_xor(m, o));
  __shared__ float redm[4], reds[4];
  if (ln == 0) redm[wv_] = m;
  __syncthreads();
  m = fmaxf(fmaxf(redm[0], redm[1]), fmaxf(redm[2], redm[3]));
  float e[8], s = 0.f;
#pragma unroll
  for (int j = 0; j < 8; j++) { e[j] = __expf(v[j] - m); s += e[j]; }
  for (int o = 32; o; o >>= 1) s += __shfl_xor(s, o);
  if (ln == 0) reds[wv_] = s;
  __syncthreads();
  s = reds[0] + reds[1] + reds[2] + reds[3];
  const float inv = 1.f / s;
  bf16x8 o8;
#pragma unroll
  for (int j = 0; j < 8; j++) o8[j] = (bf16)(e[j] * inv);
  ((bf16x8*)(S + row * 2048))[t] = o8;
}

extern "C" void kernel_launch(void* const* d_in, const int* in_sizes, int n_in,
                              void* d_out, int out_size, void* d_ws, size_t ws_size,
                              hipStream_t stream) {
  const float* x  = (const float*)d_in[0];
  const float* w1 = (const float*)d_in[1];
  const float* b1 = (const float*)d_in[2];
  const float* w2 = (const float*)d_in[3];
  const float* b2 = (const float*)d_in[4];
  const float* wq = (const float*)d_in[5];
  const float* bq = (const float*)d_in[6];
  const float* wk = (const float*)d_in[7];
  const float* bk = (const float*)d_in[8];
  const float* wv = (const float*)d_in[9];
  const float* bv = (const float*)d_in[10];
  const float* wo = (const float*)d_in[11];
  const float* bo = (const float*)d_in[12];
  float* out = (float*)d_out;

  char* ws = (char*)d_ws;
  const size_t MB = 1024ull * 1024ull;
  if (ws_size < 130 * MB) return;

  bf16* w1b  = (bf16*)(ws + 0 * MB);    // 4 MB
  bf16* w2b  = (bf16*)(ws + 4 * MB);    // 4 MB
  bf16* wqkb = (bf16*)(ws + 8 * MB);    // 4 MB: [2048][1024] = wq/32 ; wk
  bf16* wvb  = (bf16*)(ws + 12 * MB);   // 2 MB
  bf16* wob  = (bf16*)(ws + 14 * MB);   // 2 MB
  float* bqk = (float*)(ws + 16 * MB);  // 8 KB
  bf16* xb  = (bf16*)(ws + 17 * MB);    // 16 MB, dead after G1
  bf16* h1  = (bf16*)(ws + 33 * MB);    // 32 MB, dead after G2
  bf16* h   = (bf16*)(ws + 65 * MB);    // 16 MB, dead after Gqk/Gv
  bf16* qk  = (bf16*)(ws + 81 * MB);    // 32 MB [8192][2048] q-hat|k, dead after S
  bf16* vb  = (bf16*)(ws + 113 * MB);   // 16 MB, alive thru PV (residual)
  bf16* vT  = (bf16*)(ws + 17 * MB);    // 16 MB over dead xb
  bf16* S   = (bf16*)(ws + 33 * MB);    // 32 MB over dead h1 (softmax in-place)
  bf16* ctx = (bf16*)(ws + 65 * MB);    // 16 MB over dead h

  // ---- casts (wq folds 1/32 scale) + qk bias pack ----
  cast_all<<<8192, 256, 0, stream>>>(x, w1, w2, wq, wk, wv, wo,
                                     xb, w1b, w2b, wqkb, wvb, wob);
  pack_bias_qk<<<8, 256, 0, stream>>>(bq, bk, bqk);

  // ---- 1: h1 = relu(x @ w1^T + b1)   M=8192 N=2048 K=1024  [256x256 4ph]
  gemm4p<EPI_BIAS_RELU><<<dim3(8, 32, 1), 512, 0, stream>>>(
      xb, w1b, h1, b1, 1024, 1024, 1024, 2048, 0, 0, 0);
  // ---- 2: h = relu(h1 @ w2^T + b2)   M=8192 N=1024 K=2048  [128x256 2ph]
  gemm2p<EPI_BIAS_RELU><<<dim3(4, 64, 1), 512, 0, stream>>>(
      h1, w2b, h, b2, nullptr, 2048, 2048, 2048, 1024, 0, 0, 0, 0, 0);
  // ---- 3: [q/32 | k] = h @ wqkb^T + bqk   M=8192 N=2048 K=1024  [256x256 4ph]
  gemm4p<EPI_BIAS_BF16><<<dim3(8, 32, 1), 512, 0, stream>>>(
      h, wqkb, qk, bqk, 1024, 1024, 1024, 2048, 0, 0, 0);
  // ---- 4: v = h @ wv^T + bv   M=8192 N=1024 K=1024  [128x256 2ph]
  gemm2p<EPI_BIAS_BF16><<<dim3(4, 64, 1), 512, 0, stream>>>(
      h, wvb, vb, bv, nullptr, 1024, 1024, 1024, 1024, 0, 0, 0, 0, 0);
  // ---- v^T per batch (2048x1024 -> 1024x2048)
  transpose_bf16<<<dim3(16, 32, 4), 256, 0, stream>>>(
      vb, vT, 2048, 1024, 1024, 2048LL * 1024, 1024LL * 2048);
  // ---- 5: S = qhat @ k^T (scale pre-folded), batched z=4  [256x256 4ph]
  gemm4p<EPI_PLAIN_BF16><<<dim3(8, 8, 4), 512, 0, stream>>>(
      qk, qk + 1024, S, nullptr, 1024, 2048, 2048, 2048,
      2048LL * 2048, 2048LL * 2048, 2048LL * 2048);
  // ---- 6: P = softmax(S) in-place
  softmax_rows<<<8192, 256, 0, stream>>>(S);
  // ---- 7: ctx = P @ vT^T + v, batched   M=2048 N=1024 K=2048  [128x256 2ph]
  gemm2p<EPI_RESID><<<dim3(4, 16, 4), 512, 0, stream>>>(
      S, vT, ctx, nullptr, vb, 2048, 2048, 2048, 1024, 1024,
      2048LL * 2048, 1024LL * 2048, 2048LL * 1024, 2048LL * 1024);
  // ---- 8: out = ctx @ wo^T + bo (fp32)   M=8192 N=1024 K=1024  [128x256 2ph]
  gemm2p<EPI_BIAS_F32><<<dim3(4, 64, 1), 512, 0, stream>>>(
      ctx, wob, out, bo, nullptr, 1024, 1024, 1024, 1024, 0, 0, 0, 0, 0);
}

// Round 8
// 266.624 us; speedup vs baseline: 1.5414x; 1.0068x over previous
//
#include <hip/hip_runtime.h>
#include <hip/hip_bf16.h>

typedef __bf16 bf16;
typedef bf16 bf16x8 __attribute__((ext_vector_type(8)));
typedef float f32x4 __attribute__((ext_vector_type(4)));

#define EPI_BIAS_RELU  0
#define EPI_BIAS_BF16  1
#define EPI_PLAIN_BF16 2
#define EPI_RESID      3
#define EPI_BIAS_F32   4

__device__ __forceinline__ void lds_load16(const bf16* g, bf16* l) {
  __builtin_amdgcn_global_load_lds((__attribute__((address_space(1))) void*)g,
                                   (__attribute__((address_space(3))) void*)l,
                                   16, 0, 0);
}

template<int N> __device__ __forceinline__ void vmw() {
  if constexpr (N == 0) asm volatile("s_waitcnt vmcnt(0)" ::: "memory");
  else if constexpr (N == 2) asm volatile("s_waitcnt vmcnt(2)" ::: "memory");
  else if constexpr (N == 4) asm volatile("s_waitcnt vmcnt(4)" ::: "memory");
}
__device__ __forceinline__ void barrier() { asm volatile("s_barrier" ::: "memory"); }

// Row-slab XCD mapping (r7-proven: FETCH near-ideal): XCD x owns a contiguous
// (z,by) slab; bx varies fastest. Bijective when (gy*gz)%8==0.
__device__ __forceinline__ void xcd_map(int& bx, int& by, int& z) {
  const int gx = gridDim.x, gy = gridDim.y;
  const int Y8 = (gy * gridDim.z) >> 3;
  const int L = (blockIdx.z * gy + blockIdx.y) * gx + blockIdx.x;
  const int xcd = L & 7, j = L >> 3;
  bx = j % gx;
  const int yy = xcd * Y8 + j / gx;
  by = yy % gy;
  z  = yy / gy;
}

// ============ 256x256 tile, 2-phase/K-tile, 32-MFMA clusters ============
// p0: read A-full(t)+B0(t) [20 ds_read] | stage B-full(t+1) | bar | 32 MFMA | bar
// p1: read B1(t) [4 ds_read]            | stage A-full(t+2) + vmcnt(4) | bar | 32 MFMA | bar
// FIFO (4 loads/issue-group/wave): at p1(t)'s wait, outstanding =
// [A(t+1) from p1(t-1), B(t+1) from p0(t), A(t+2) just issued]; vmcnt(4)
// forces A(t+1)+B(t+1), leaves A(t+2). Both barriers after the wait precede
// p0(t+1)'s reads -> race-free. Overwrites: B(t+1)->lB[nxt] issued 2 barriers
// after last read of B1(t-1); A(t+2)->lA[cur] issued 1+ barrier after last
// read of A(t) (p0(t), drained pre-mid-barrier). Tail: vmcnt(0) at t=NT-2.
template<int EPI>
__global__ __launch_bounds__(512, 2)
void gemm2x(const bf16* __restrict__ A, const bf16* __restrict__ B,
            void* __restrict__ Cv, const float* __restrict__ bias,
            int K, int lda, int ldb, int ldc,
            long long sAz, long long sBz, long long sCz)
{
  constexpr int BK = 64;
  constexpr int M_REP = 8, N_REP = 4, NH = 2;

  __shared__ __align__(16) bf16 lA[2][256 * BK];
  __shared__ __align__(16) bf16 lB[2][256 * BK];

  int bx, by, z;
  xcd_map(bx, by, z);

  const bf16* Ab = A + (size_t)z * sAz;
  const bf16* Bb = B + (size_t)z * sBz;
  const int row0 = by * 256, col0 = bx * 256;
  const int tid = threadIdx.x, w = tid >> 6, l = tid & 63;
  const int wr = w >> 2, wc = w & 3;

  const int srow = l >> 3, scb = (l & 7) ^ srow;
  const bf16* gA = Ab + (size_t)(row0 + w * 8 + srow) * lda + scb * 8;
  const bf16* gB = Bb + (size_t)(col0 + w * 8 + srow) * ldb + scb * 8;

  auto issueA = [&](int buf, int k0) {
#pragma unroll
    for (int i = 0; i < 4; i++)
      lds_load16(gA + (size_t)(i * 64) * lda + k0,
                 &lA[buf][(i * 64 + w * 8) * BK]);
  };
  auto issueB = [&](int buf, int k0) {
#pragma unroll
    for (int i = 0; i < 4; i++)
      lds_load16(gB + (size_t)(i * 64) * ldb + k0,
                 &lB[buf][(i * 64 + w * 8) * BK]);
  };

  const int fr = l & 15, fq = l >> 4, sw = fr & 7;
  bf16x8 aA[M_REP][2], bB0[NH][2], bB1[NH][2];
  f32x4 acc[M_REP][N_REP] = {};

  auto readAfull = [&](int buf) {
#pragma unroll
    for (int m = 0; m < M_REP; m++) {
      const int r = (m >> 2) * 128 + wr * 64 + (m & 3) * 16 + fr;
      const bf16* base = &lA[buf][r * BK];
#pragma unroll
      for (int kk = 0; kk < 2; kk++)
        aA[m][kk] = *(const bf16x8*)(base + ((kk * 4 + fq) ^ sw) * 8);
    }
  };
  auto readB = [&](bf16x8 (&dst)[NH][2], int buf, int h) {
#pragma unroll
    for (int nn = 0; nn < NH; nn++) {
      const bf16* base = &lB[buf][(h * 128 + wc * 32 + nn * 16 + fr) * BK];
#pragma unroll
      for (int kk = 0; kk < 2; kk++)
        dst[nn][kk] = *(const bf16x8*)(base + ((kk * 4 + fq) ^ sw) * 8);
    }
  };
  auto quad32 = [&](const bf16x8 (&b)[NH][2], int nBase) {
    __builtin_amdgcn_s_setprio(1);
#pragma unroll
    for (int m = 0; m < M_REP; m++)
#pragma unroll
      for (int nh = 0; nh < NH; nh++)
#pragma unroll
        for (int kk = 0; kk < 2; kk++)
          acc[m][nBase + nh] = __builtin_amdgcn_mfma_f32_16x16x32_bf16(
              aA[m][kk], b[nh][kk], acc[m][nBase + nh], 0, 0, 0);
    __builtin_amdgcn_s_setprio(0);
  };

  const int NT = K / BK;
  // prologue: A(0),B(0),A(1); vmcnt(4) leaves A(1) outstanding
  issueA(0, 0); issueB(0, 0); issueA(1, BK);
  vmw<4>();
  barrier();

  for (int t = 0; t < NT; t++) {
    const int cur = t & 1, nxt = cur ^ 1;
    const bool s1 = (t + 1 < NT), s2 = (t + 2 < NT);
    // p0
    readAfull(cur);
    readB(bB0, cur, 0);
    if (s1) issueB(nxt, (t + 1) * BK);
    barrier();
    quad32(bB0, 0);
    barrier();
    // p1
    readB(bB1, cur, 1);
    if (s2) { issueA(cur, (t + 2) * BK); vmw<4>(); }
    else vmw<0>();
    barrier();
    quad32(bB1, NH);
    barrier();
  }

  // epilogue: C/D layout col=lane&15, row=(lane>>4)*4+j  [verified m89]
#pragma unroll
  for (int m = 0; m < M_REP; m++) {
#pragma unroll
    for (int n = 0; n < N_REP; n++) {
      const int col = col0 + (n / NH) * 128 + wc * 32 + (n % NH) * 16 + fr;
#pragma unroll
      for (int j = 0; j < 4; j++) {
        const int rrow = row0 + (m >> 2) * 128 + wr * 64 + (m & 3) * 16 + fq * 4 + j;
        const float val = acc[m][n][j];
        if constexpr (EPI == EPI_PLAIN_BF16) {
          bf16* Cp = (bf16*)Cv + (size_t)z * sCz;
          Cp[(size_t)rrow * ldc + col] = (bf16)val;
        } else if constexpr (EPI == EPI_BIAS_BF16) {
          bf16* Cp = (bf16*)Cv;
          Cp[(size_t)rrow * ldc + col] = (bf16)(val + bias[col]);
        } else if constexpr (EPI == EPI_BIAS_RELU) {
          bf16* Cp = (bf16*)Cv;
          Cp[(size_t)rrow * ldc + col] = (bf16)fmaxf(val + bias[col], 0.f);
        }
      }
    }
  }
}

// ============ 128x256 tile, 2-phase (r6-proven, unchanged) ============
template<int EPI>
__global__ __launch_bounds__(512, 2)
void gemm2p(const bf16* __restrict__ A, const bf16* __restrict__ B,
            void* __restrict__ Cv, const float* __restrict__ bias,
            const bf16* __restrict__ resid,
            int K, int lda, int ldb, int ldc, int ldr,
            long long sAz, long long sBz, long long sCz, long long sRz)
{
  constexpr int BM = 128, BK = 64;
  constexpr int M_REP = 4, NH = 2;

  __shared__ __align__(16) bf16 lA[2][BM * BK];
  __shared__ __align__(16) bf16 lB[2][256 * BK];

  int bx, by, z;
  xcd_map(bx, by, z);

  const bf16* Ab = A + (size_t)z * sAz;
  const bf16* Bb = B + (size_t)z * sBz;
  const int row0 = by * BM, col0 = bx * 256;
  const int tid = threadIdx.x, w = tid >> 6, l = tid & 63;
  const int wr = w >> 2, wc = w & 3;

  const int srow = l >> 3, scb = (l & 7) ^ srow;
  const bf16* gA = Ab + (size_t)(row0 + w * 8 + srow) * lda + scb * 8;
  const bf16* gB = Bb + (size_t)(col0 + w * 8 + srow) * ldb + scb * 8;

  auto issueAfull = [&](int buf, int k0) {
#pragma unroll
    for (int i = 0; i < 2; i++)
      lds_load16(gA + (size_t)(i * 64) * lda + k0,
                 &lA[buf][(i * 64 + w * 8) * BK]);
  };
  auto issueBfull = [&](int buf, int k0) {
#pragma unroll
    for (int i = 0; i < 4; i++)
      lds_load16(gB + (size_t)(i * 64) * ldb + k0,
                 &lB[buf][(i * 64 + w * 8) * BK]);
  };

  const int fr = l & 15, fq = l >> 4, sw = fr & 7;
  bf16x8 aA[M_REP][2], bB0[NH][2], bB1[NH][2];
  f32x4 acc[M_REP][4] = {};

  auto readAfull = [&](int buf) {
#pragma unroll
    for (int m = 0; m < M_REP; m++) {
      const bf16* base = &lA[buf][(wr * 64 + m * 16 + fr) * BK];
#pragma unroll
      for (int kk = 0; kk < 2; kk++)
        aA[m][kk] = *(const bf16x8*)(base + ((kk * 4 + fq) ^ sw) * 8);
    }
  };
  auto readB = [&](bf16x8 (&dst)[NH][2], int buf, int h) {
#pragma unroll
    for (int nn = 0; nn < NH; nn++) {
      const bf16* base = &lB[buf][(h * 128 + wc * 32 + nn * 16 + fr) * BK];
#pragma unroll
      for (int kk = 0; kk < 2; kk++)
        dst[nn][kk] = *(const bf16x8*)(base + ((kk * 4 + fq) ^ sw) * 8);
    }
  };
  auto quad2 = [&](const bf16x8 (&b)[NH][2], int nBase) {
    __builtin_amdgcn_s_setprio(1);
#pragma unroll
    for (int m = 0; m < M_REP; m++)
#pragma unroll
      for (int nh = 0; nh < NH; nh++)
#pragma unroll
        for (int kk = 0; kk < 2; kk++)
          acc[m][nBase + nh] = __builtin_amdgcn_mfma_f32_16x16x32_bf16(
              aA[m][kk], b[nh][kk], acc[m][nBase + nh], 0, 0, 0);
    __builtin_amdgcn_s_setprio(0);
  };

  const int NT = K / BK;
  issueAfull(0, 0); issueBfull(0, 0); issueAfull(1, BK);
  vmw<2>();
  barrier();

  for (int t = 0; t < NT; t++) {
    const int cur = t & 1, nxt = cur ^ 1;
    const bool s1 = (t + 1 < NT), s2 = (t + 2 < NT);
    readAfull(cur);
    readB(bB0, cur, 0);
    if (s1) issueBfull(nxt, (t + 1) * BK);
    barrier();
    quad2(bB0, 0);
    barrier();
    readB(bB1, cur, 1);
    if (s2) { issueAfull(cur, (t + 2) * BK); vmw<2>(); }
    else vmw<0>();
    barrier();
    quad2(bB1, NH);
    barrier();
  }

#pragma unroll
  for (int m = 0; m < M_REP; m++) {
#pragma unroll
    for (int n = 0; n < 4; n++) {
      const int col = col0 + (n / NH) * 128 + wc * 32 + (n % NH) * 16 + fr;
#pragma unroll
      for (int j = 0; j < 4; j++) {
        const int rrow = row0 + wr * 64 + m * 16 + fq * 4 + j;
        const float val = acc[m][n][j];
        if constexpr (EPI == EPI_PLAIN_BF16) {
          bf16* Cp = (bf16*)Cv + (size_t)z * sCz;
          Cp[(size_t)rrow * ldc + col] = (bf16)val;
        } else if constexpr (EPI == EPI_BIAS_F32) {
          float* Cp = (float*)Cv;
          Cp[(size_t)rrow * ldc + col] = val + bias[col];
        } else if constexpr (EPI == EPI_BIAS_BF16) {
          bf16* Cp = (bf16*)Cv;
          Cp[(size_t)rrow * ldc + col] = (bf16)(val + bias[col]);
        } else if constexpr (EPI == EPI_BIAS_RELU) {
          bf16* Cp = (bf16*)Cv;
          Cp[(size_t)rrow * ldc + col] = (bf16)fmaxf(val + bias[col], 0.f);
        } else {  // EPI_RESID
          bf16* Cp = (bf16*)Cv + (size_t)z * sCz;
          const bf16* Rp = resid + (size_t)z * sRz;
          Cp[(size_t)rrow * ldc + col] = (bf16)(val + (float)Rp[(size_t)rrow * ldr + col]);
        }
      }
    }
  }
}

// ===== single cast kernel: x + all weights (block-range dispatch) =====
__global__ __launch_bounds__(256)
void cast_all(const float* __restrict__ x,  const float* __restrict__ w1,
              const float* __restrict__ w2, const float* __restrict__ wq,
              const float* __restrict__ wk, const float* __restrict__ wv,
              const float* __restrict__ wo,
              bf16* __restrict__ xb, bf16* __restrict__ w1b,
              bf16* __restrict__ w2b, bf16* __restrict__ wqkb,
              bf16* __restrict__ wvb, bf16* __restrict__ wob) {
  const int b = blockIdx.x;
  const float* src; bf16* dst; int base; float scale = 1.f;
  if (b < 4096)      { src = x;  dst = xb;   base = b; }
  else if (b < 5120) { src = w1; dst = w1b;  base = b - 4096; }
  else if (b < 6144) { src = w2; dst = w2b;  base = b - 5120; }
  else if (b < 6656) { src = wq; dst = wqkb;              base = b - 6144; scale = 0.03125f; }
  else if (b < 7168) { src = wk; dst = wqkb + (1 << 20);  base = b - 6656; }
  else if (b < 7680) { src = wv; dst = wvb;  base = b - 7168; }
  else               { src = wo; dst = wob;  base = b - 7680; }
  const int i = base * 256 + threadIdx.x;
  const float4* p = (const float4*)src;
  float4 a = p[2 * i], c = p[2 * i + 1];
  bf16x8 o8;
  o8[0] = (bf16)(a.x * scale); o8[1] = (bf16)(a.y * scale);
  o8[2] = (bf16)(a.z * scale); o8[3] = (bf16)(a.w * scale);
  o8[4] = (bf16)(c.x * scale); o8[5] = (bf16)(c.y * scale);
  o8[6] = (bf16)(c.z * scale); o8[7] = (bf16)(c.w * scale);
  ((bf16x8*)dst)[i] = o8;
}

__global__ __launch_bounds__(256)
void pack_bias_qk(const float* __restrict__ bq, const float* __restrict__ bk,
                  float* __restrict__ o) {
  int i = blockIdx.x * 256 + threadIdx.x;  // 2048
  o[i] = (i < 1024) ? bq[i] * 0.03125f : bk[i - 1024];
}

// batched transpose: in (z, R x C, ld ldi) -> out (z, C x R)
__global__ __launch_bounds__(256)
void transpose_bf16(const bf16* __restrict__ in, bf16* __restrict__ out,
                    int R, int C, int ldi,
                    long long inZ, long long outZ) {
  __shared__ bf16 t[64][72];
  const bf16* ib = in + (size_t)blockIdx.z * inZ;
  bf16* ob = out + (size_t)blockIdx.z * outZ;
  const int r0 = blockIdx.y * 64, c0 = blockIdx.x * 64;
  const int tid = threadIdx.x;
#pragma unroll
  for (int p = 0; p < 2; p++) {
    int r = p * 32 + tid / 8, cc = (tid % 8) * 8;
    bf16x8 vv = *(const bf16x8*)(ib + (size_t)(r0 + r) * ldi + c0 + cc);
#pragma unroll
    for (int j = 0; j < 8; j++) t[r][cc + j] = vv[j];
  }
  __syncthreads();
#pragma unroll
  for (int p = 0; p < 2; p++) {
    int r = p * 32 + tid / 8, cc = (tid % 8) * 8;
    bf16x8 o;
#pragma unroll
    for (int j = 0; j < 8; j++) o[j] = t[cc + j][r];
    *(bf16x8*)(ob + (size_t)(c0 + r) * R + r0 + cc) = o;
  }
}

// row softmax in-place: S (nrows x 2048 bf16)
__global__ __launch_bounds__(256)
void softmax_rows(bf16* __restrict__ S) {
  const size_t row = blockIdx.x;
  const int t = threadIdx.x, wv_ = t >> 6, ln = t & 63;
  bf16x8 v8 = ((const bf16x8*)(S + row * 2048))[t];
  float v[8];
#pragma unroll
  for (int j = 0; j < 8; j++) v[j] = (float)v8[j];
  float m = v[0];
#pragma unroll
  for (int j = 1; j < 8; j++) m = fmaxf(m, v[j]);
  for (int o = 32; o; o >>= 1) m = fmaxf(m, __shfl_xor(m, o));
  __shared__ float redm[4], reds[4];
  if (ln == 0) redm[wv_] = m;
  __syncthreads();
  m = fmaxf(fmaxf(redm[0], redm[1]), fmaxf(redm[2], redm[3]));
  float e[8], s = 0.f;
#pragma unroll
  for (int j = 0; j < 8; j++) { e[j] = __expf(v[j] - m); s += e[j]; }
  for (int o = 32; o; o >>= 1) s += __shfl_xor(s, o);
  if (ln == 0) reds[wv_] = s;
  __syncthreads();
  s = reds[0] + reds[1] + reds[2] + reds[3];
  const float inv = 1.f / s;
  bf16x8 o8;
#pragma unroll
  for (int j = 0; j < 8; j++) o8[j] = (bf16)(e[j] * inv);
  ((bf16x8*)(S + row * 2048))[t] = o8;
}

extern "C" void kernel_launch(void* const* d_in, const int* in_sizes, int n_in,
                              void* d_out, int out_size, void* d_ws, size_t ws_size,
                              hipStream_t stream) {
  const float* x  = (const float*)d_in[0];
  const float* w1 = (const float*)d_in[1];
  const float* b1 = (const float*)d_in[2];
  const float* w2 = (const float*)d_in[3];
  const float* b2 = (const float*)d_in[4];
  const float* wq = (const float*)d_in[5];
  const float* bq = (const float*)d_in[6];
  const float* wk = (const float*)d_in[7];
  const float* bk = (const float*)d_in[8];
  const float* wv = (const float*)d_in[9];
  const float* bv = (const float*)d_in[10];
  const float* wo = (const float*)d_in[11];
  const float* bo = (const float*)d_in[12];
  float* out = (float*)d_out;

  char* ws = (char*)d_ws;
  const size_t MB = 1024ull * 1024ull;
  if (ws_size < 130 * MB) return;

  bf16* w1b  = (bf16*)(ws + 0 * MB);    // 4 MB
  bf16* w2b  = (bf16*)(ws + 4 * MB);    // 4 MB
  bf16* wqkb = (bf16*)(ws + 8 * MB);    // 4 MB: [2048][1024] = wq/32 ; wk
  bf16* wvb  = (bf16*)(ws + 12 * MB);   // 2 MB
  bf16* wob  = (bf16*)(ws + 14 * MB);   // 2 MB
  float* bqk = (float*)(ws + 16 * MB);  // 8 KB
  bf16* xb  = (bf16*)(ws + 17 * MB);    // 16 MB, dead after G1
  bf16* h1  = (bf16*)(ws + 33 * MB);    // 32 MB, dead after G2
  bf16* h   = (bf16*)(ws + 65 * MB);    // 16 MB, dead after Gqk/Gv
  bf16* qk  = (bf16*)(ws + 81 * MB);    // 32 MB [8192][2048] q-hat|k, dead after S
  bf16* vb  = (bf16*)(ws + 113 * MB);   // 16 MB, alive thru PV (residual)
  bf16* vT  = (bf16*)(ws + 17 * MB);    // 16 MB over dead xb
  bf16* S   = (bf16*)(ws + 33 * MB);    // 32 MB over dead h1 (softmax in-place)
  bf16* ctx = (bf16*)(ws + 65 * MB);    // 16 MB over dead h

  // ---- casts (wq folds 1/32 scale) + qk bias pack ----
  cast_all<<<8192, 256, 0, stream>>>(x, w1, w2, wq, wk, wv, wo,
                                     xb, w1b, w2b, wqkb, wvb, wob);
  pack_bias_qk<<<8, 256, 0, stream>>>(bq, bk, bqk);

  // ---- 1: h1 = relu(x @ w1^T + b1)   M=8192 N=2048 K=1024  [256x256 2ph]
  gemm2x<EPI_BIAS_RELU><<<dim3(8, 32, 1), 512, 0, stream>>>(
      xb, w1b, h1, b1, 1024, 1024, 1024, 2048, 0, 0, 0);
  // ---- 2: h = relu(h1 @ w2^T + b2)   M=8192 N=1024 K=2048  [128x256 2ph]
  gemm2p<EPI_BIAS_RELU><<<dim3(4, 64, 1), 512, 0, stream>>>(
      h1, w2b, h, b2, nullptr, 2048, 2048, 2048, 1024, 0, 0, 0, 0, 0);
  // ---- 3: [q/32 | k] = h @ wqkb^T + bqk   M=8192 N=2048 K=1024  [256x256 2ph]
  gemm2x<EPI_BIAS_BF16><<<dim3(8, 32, 1), 512, 0, stream>>>(
      h, wqkb, qk, bqk, 1024, 1024, 1024, 2048, 0, 0, 0);
  // ---- 4: v = h @ wv^T + bv   M=8192 N=1024 K=1024  [128x256 2ph]
  gemm2p<EPI_BIAS_BF16><<<dim3(4, 64, 1), 512, 0, stream>>>(
      h, wvb, vb, bv, nullptr, 1024, 1024, 1024, 1024, 0, 0, 0, 0, 0);
  // ---- v^T per batch (2048x1024 -> 1024x2048)
  transpose_bf16<<<dim3(16, 32, 4), 256, 0, stream>>>(
      vb, vT, 2048, 1024, 1024, 2048LL * 1024, 1024LL * 2048);
  // ---- 5: S = qhat @ k^T (scale pre-folded), batched z=4  [256x256 2ph]
  gemm2x<EPI_PLAIN_BF16><<<dim3(8, 8, 4), 512, 0, stream>>>(
      qk, qk + 1024, S, nullptr, 1024, 2048, 2048, 2048,
      2048LL * 2048, 2048LL * 2048, 2048LL * 2048);
  // ---- 6: P = softmax(S) in-place
  softmax_rows<<<8192, 256, 0, stream>>>(S);
  // ---- 7: ctx = P @ vT^T + v, batched   M=2048 N=1024 K=2048  [128x256 2ph]
  gemm2p<EPI_RESID><<<dim3(4, 16, 4), 512, 0, stream>>>(
      S, vT, ctx, nullptr, vb, 2048, 2048, 2048, 1024, 1024,
      2048LL * 2048, 1024LL * 2048, 2048LL * 1024, 2048LL * 1024);
  // ---- 8: out = ctx @ wo^T + bo (fp32)   M=8192 N=1024 K=1024  [128x256 2ph]
  gemm2p<EPI_BIAS_F32><<<dim3(4, 64, 1), 512, 0, stream>>>(
      ctx, wob, out, bo, nullptr, 1024, 1024, 1024, 1024, 0, 0, 0, 0, 0);
}